// Round 1
// baseline (2882.307 us; speedup 1.0000x reference)
//
#include <hip/hip_runtime.h>
#include <hip/hip_bf16.h>
#include <cstdint>

// MiniMax M2 decoder layer, fp32 baseline (no MFMA; CDNA4 has no fp32 MFMA).
// Pipeline:
//  1. rmsnorm(hidden, ln1) -> xn
//  2. packed GEMM xn @ {wq,wk,wv} -> Q,K,V
//  3. q/k rmsnorm + partial RoPE (in-place on Q,K)
//  4. causal GQA flash attention -> AO
//  5. AO @ wo + hidden -> d_out          (residual 1)
//  6. rmsnorm(d_out, ln2) -> xn
//  7. gate logits, sigmoid top-2 routing, 128-aligned expert segments
//  8. grouped GEMM: silu(xn@w1_e)*(xn@w3_e) -> Hb ; Hb @ w2_e * rw -> Yb
//  9. d_out += Yb[slot0] + Yb[slot1]     (residual 2, deterministic)

#define SDIM 2048
#define HDIM 2048
#define NHQ 16
#define NKVH 4
#define HD 128
#define RDIM 64
#define NEXP 8
#define IDIM 1024
#define CAP 5120                       // 4096 slots + 8*128 alignment padding
#define ATT_SCALE 0.08838834764831845f // 128^-0.5
#define EPS 1e-6f

// ---------------------------------------------------------------- reductions
__device__ __forceinline__ float block_reduce_sum_256(float v) {
  __shared__ float sb[4];
#pragma unroll
  for (int off = 32; off > 0; off >>= 1) v += __shfl_down(v, off, 64);
  int lane = threadIdx.x & 63, wid = threadIdx.x >> 6;
  if (lane == 0) sb[wid] = v;
  __syncthreads();
  return sb[0] + sb[1] + sb[2] + sb[3];
}

// ---------------------------------------------------------------- rmsnorm H=2048
__global__ __launch_bounds__(256) void k_rmsnorm2048(
    const float* __restrict__ x, const float* __restrict__ w, float* __restrict__ out) {
  int row = blockIdx.x;
  const float* xr = x + (size_t)row * HDIM;
  float* orow = out + (size_t)row * HDIM;
  int i0 = threadIdx.x * 4, i1 = i0 + 1024;
  float4 a = *(const float4*)(xr + i0);
  float4 b = *(const float4*)(xr + i1);
  float ss = a.x*a.x + a.y*a.y + a.z*a.z + a.w*a.w +
             b.x*b.x + b.y*b.y + b.z*b.z + b.w*b.w;
  float tot = block_reduce_sum_256(ss);
  float r = rsqrtf(tot * (1.0f / HDIM) + EPS);
  float4 wa = *(const float4*)(w + i0);
  float4 wb = *(const float4*)(w + i1);
  float4 oa, ob;
  oa.x = wa.x * (a.x * r); oa.y = wa.y * (a.y * r);
  oa.z = wa.z * (a.z * r); oa.w = wa.w * (a.w * r);
  ob.x = wb.x * (b.x * r); ob.y = wb.y * (b.y * r);
  ob.z = wb.z * (b.z * r); ob.w = wb.w * (b.w * r);
  *(float4*)(orow + i0) = oa;
  *(float4*)(orow + i1) = ob;
}

// ---------------------------------------------------------------- q/k norm + rope
__global__ __launch_bounds__(256) void k_qknorm_rope(
    float* __restrict__ X, const float* __restrict__ w,
    const float* __restrict__ cosb, const float* __restrict__ sinb, int len) {
  int row = blockIdx.x;
  float* xr = X + (size_t)row * len;
  __shared__ float xs[HDIM];
  float ss = 0.f;
  for (int i = threadIdx.x * 4; i < len; i += 1024) {
    float4 v = *(const float4*)(xr + i);
    *(float4*)(xs + i) = v;
    ss += v.x*v.x + v.y*v.y + v.z*v.z + v.w*v.w;
  }
  float tot = block_reduce_sum_256(ss);  // internal barrier also covers xs stores
  float r = rsqrtf(tot / (float)len + EPS);
  const float* cr = cosb + (size_t)row * RDIM;
  const float* sr = sinb + (size_t)row * RDIM;
  for (int i = threadIdx.x; i < len; i += 256) {
    int d = i & (HD - 1);
    float xv = xs[i] * r * w[i];
    float o;
    if (d < RDIM) {
      float c = cr[d], s = sr[d];
      if (d < RDIM / 2) {
        float pn = xs[i + RDIM / 2] * r * w[i + RDIM / 2];
        o = xv * c - pn * s;
      } else {
        float pn = xs[i - RDIM / 2] * r * w[i - RDIM / 2];
        o = xv * c + pn * s;
      }
    } else {
      o = xv;
    }
    xr[i] = o;
  }
}

// ---------------------------------------------------------------- GEMM (128x128x16, 8x8 microtile)
struct GArgs {
  const float* A; int lda;
  const float* B; const float* B2; int ldb;
  float* C; int ldc;
  const float* resid;   // MODE1
  const int* perm;      // MODE2/3
  const float* rwbuf;   // MODE3
  const int* aoff;      // MODE2/3
  int Kdim;
  const float* Bq; const float* Bk; const float* Bv;  // MODE0
  float* Cq; float* Ck; float* Cv;                    // MODE0
};

__device__ __forceinline__ void fma16(float (&c)[4][4], const float4& a, const float4& b) {
  c[0][0] = fmaf(a.x, b.x, c[0][0]); c[0][1] = fmaf(a.x, b.y, c[0][1]);
  c[0][2] = fmaf(a.x, b.z, c[0][2]); c[0][3] = fmaf(a.x, b.w, c[0][3]);
  c[1][0] = fmaf(a.y, b.x, c[1][0]); c[1][1] = fmaf(a.y, b.y, c[1][1]);
  c[1][2] = fmaf(a.y, b.z, c[1][2]); c[1][3] = fmaf(a.y, b.w, c[1][3]);
  c[2][0] = fmaf(a.z, b.x, c[2][0]); c[2][1] = fmaf(a.z, b.y, c[2][1]);
  c[2][2] = fmaf(a.z, b.z, c[2][2]); c[2][3] = fmaf(a.z, b.w, c[2][3]);
  c[3][0] = fmaf(a.w, b.x, c[3][0]); c[3][1] = fmaf(a.w, b.y, c[3][1]);
  c[3][2] = fmaf(a.w, b.z, c[3][2]); c[3][3] = fmaf(a.w, b.w, c[3][3]);
}

__device__ __forceinline__ float siluf(float x) { return x / (1.0f + expf(-x)); }

// MODE 0: packed QKV (B/C chosen per n-tile).  MODE 1: C = A@B + resid.
// MODE 2: gathered rows, dual-B, store silu(AB)*(AB2).  MODE 3: store (A@B)*rw.
template <int MODE>
__global__ __launch_bounds__(256) void k_gemm(GArgs g) {
  __shared__ float As[16][132];
  __shared__ float Bs[16][132];
  __shared__ float B2s[(MODE == 2) ? 16 : 1][132];

  int tid = threadIdx.x;
  int tx = tid & 15, ty = tid >> 4;
  int m0 = blockIdx.y * 128;
  int n0 = blockIdx.x * 128;

  const float* A = g.A;
  const float* B; const float* B2 = nullptr;
  float* C;
  int lda = g.lda, ldb, ldc;
  int expert = 0;

  if (MODE == 0) {
    int nt = blockIdx.x;
    if (nt < 16)      { B = g.Bq; ldb = 2048; C = g.Cq; ldc = 2048; n0 = nt * 128; }
    else if (nt < 20) { B = g.Bk; ldb = 512;  C = g.Ck; ldc = 512;  n0 = (nt - 16) * 128; }
    else              { B = g.Bv; ldb = 512;  C = g.Cv; ldc = 512;  n0 = (nt - 20) * 128; }
  } else {
    B = g.B; ldb = g.ldb; C = g.C; ldc = g.ldc;
  }
  if (MODE == 2 || MODE == 3) {
    if (m0 >= g.aoff[8]) return;
    while (g.aoff[expert + 1] <= m0) expert++;
    size_t boff = (size_t)expert * (size_t)g.Kdim * (size_t)ldb;
    B += boff;
    if (MODE == 2) B2 = g.B2 + boff;
  }

  // A staging: thread loads rows (arow, arow+64), k-chunk akc..akc+3
  int arow = tid >> 2;
  int akc = (tid & 3) << 2;
  const float* ap0; const float* ap1;
  bool av0 = true, av1 = true;
  if (MODE == 2) {
    int j0 = m0 + arow, j1 = j0 + 64;
    int t0 = g.perm[j0], t1 = g.perm[j1];
    av0 = (t0 >= 0); av1 = (t1 >= 0);
    ap0 = A + (size_t)(av0 ? t0 : 0) * lda + akc;
    ap1 = A + (size_t)(av1 ? t1 : 0) * lda + akc;
  } else {
    ap0 = A + (size_t)(m0 + arow) * lda + akc;
    ap1 = A + (size_t)(m0 + arow + 64) * lda + akc;
  }
  // B staging: rows (bkr, bkr+8), 4 cols at bnc
  int bkr = tid >> 5;
  int bnc = (tid & 31) << 2;
  const float* bp0 = B + (size_t)bkr * ldb + n0 + bnc;
  const float* bp1 = B + (size_t)(bkr + 8) * ldb + n0 + bnc;
  const float* cp0 = nullptr; const float* cp1 = nullptr;
  if (MODE == 2) {
    cp0 = B2 + (size_t)bkr * ldb + n0 + bnc;
    cp1 = B2 + (size_t)(bkr + 8) * ldb + n0 + bnc;
  }

  float acc[2][2][4][4] = {};
  float acc2[2][2][4][4] = {};

  const float4 fz = make_float4(0.f, 0.f, 0.f, 0.f);
  float4 ra0 = av0 ? *(const float4*)(ap0) : fz;
  float4 ra1 = av1 ? *(const float4*)(ap1) : fz;
  float4 rb0 = *(const float4*)(bp0);
  float4 rb1 = *(const float4*)(bp1);
  float4 rc0, rc1;
  if (MODE == 2) { rc0 = *(const float4*)(cp0); rc1 = *(const float4*)(cp1); }

  for (int k0 = 0; k0 < g.Kdim; k0 += 16) {
    As[akc + 0][arow] = ra0.x; As[akc + 1][arow] = ra0.y;
    As[akc + 2][arow] = ra0.z; As[akc + 3][arow] = ra0.w;
    As[akc + 0][arow + 64] = ra1.x; As[akc + 1][arow + 64] = ra1.y;
    As[akc + 2][arow + 64] = ra1.z; As[akc + 3][arow + 64] = ra1.w;
    *(float4*)&Bs[bkr][bnc] = rb0;
    *(float4*)&Bs[bkr + 8][bnc] = rb1;
    if (MODE == 2) {
      *(float4*)&B2s[bkr][bnc] = rc0;
      *(float4*)&B2s[bkr + 8][bnc] = rc1;
    }
    __syncthreads();

    int kn = k0 + 16;
    if (kn < g.Kdim) {  // prefetch next k-tile while computing
      ra0 = av0 ? *(const float4*)(ap0 + kn) : fz;
      ra1 = av1 ? *(const float4*)(ap1 + kn) : fz;
      rb0 = *(const float4*)(bp0 + (size_t)kn * ldb);
      rb1 = *(const float4*)(bp1 + (size_t)kn * ldb);
      if (MODE == 2) {
        rc0 = *(const float4*)(cp0 + (size_t)kn * ldb);
        rc1 = *(const float4*)(cp1 + (size_t)kn * ldb);
      }
    }

#pragma unroll
    for (int kk = 0; kk < 16; kk++) {
      float4 al = *(float4*)&As[kk][ty * 4];
      float4 ah = *(float4*)&As[kk][64 + ty * 4];
      float4 bl = *(float4*)&Bs[kk][tx * 4];
      float4 bh = *(float4*)&Bs[kk][64 + tx * 4];
      fma16(acc[0][0], al, bl); fma16(acc[0][1], al, bh);
      fma16(acc[1][0], ah, bl); fma16(acc[1][1], ah, bh);
      if (MODE == 2) {
        float4 cl = *(float4*)&B2s[kk][tx * 4];
        float4 ch = *(float4*)&B2s[kk][64 + tx * 4];
        fma16(acc2[0][0], al, cl); fma16(acc2[0][1], al, ch);
        fma16(acc2[1][0], ah, cl); fma16(acc2[1][1], ah, ch);
      }
    }
    __syncthreads();
  }

  // epilogue
#pragma unroll
  for (int rh = 0; rh < 2; rh++) {
#pragma unroll
    for (int i = 0; i < 4; i++) {
      int row = m0 + rh * 64 + ty * 4 + i;
#pragma unroll
      for (int ch = 0; ch < 2; ch++) {
        int col = n0 + ch * 64 + tx * 4;
        float4 v;
        v.x = acc[rh][ch][i][0]; v.y = acc[rh][ch][i][1];
        v.z = acc[rh][ch][i][2]; v.w = acc[rh][ch][i][3];
        if (MODE == 0) {
          *(float4*)&C[(size_t)row * ldc + col] = v;
        } else if (MODE == 1) {
          float4 rv = *(const float4*)(g.resid + (size_t)row * 2048 + col);
          v.x += rv.x; v.y += rv.y; v.z += rv.z; v.w += rv.w;
          *(float4*)&C[(size_t)row * ldc + col] = v;
        } else if (MODE == 2) {
          if (g.perm[row] >= 0) {
            float4 u;
            u.x = acc2[rh][ch][i][0]; u.y = acc2[rh][ch][i][1];
            u.z = acc2[rh][ch][i][2]; u.w = acc2[rh][ch][i][3];
            v.x = siluf(v.x) * u.x; v.y = siluf(v.y) * u.y;
            v.z = siluf(v.z) * u.z; v.w = siluf(v.w) * u.w;
            *(float4*)&C[(size_t)row * ldc + col] = v;
          }
        } else {  // MODE 3
          if (g.perm[row] >= 0) {
            float sc = g.rwbuf[row];
            v.x *= sc; v.y *= sc; v.z *= sc; v.w *= sc;
            *(float4*)&C[(size_t)row * ldc + col] = v;
          }
        }
      }
    }
  }
}

// ---------------------------------------------------------------- flash attention
__global__ __launch_bounds__(256) void k_attn(
    const float* __restrict__ Qb, const float* __restrict__ Kb,
    const float* __restrict__ Vb, float* __restrict__ AO) {
  __shared__ float Qs[32][132];
  __shared__ float Ks[32][132];
  __shared__ float Vs[32][132];
  __shared__ float Ss[32][36];
  int h = blockIdx.y;
  int q0 = blockIdx.x * 32;
  int hk = h >> 2;  // GQA: 4 q-heads per kv-head
  int tid = threadIdx.x;
  int r = tid >> 3;   // q-row within tile
  int cb = tid & 7;   // column-group / dim-group

  for (int l = tid; l < 1024; l += 256) {
    int rr = l >> 5, cc = (l & 31) << 2;
    *(float4*)&Qs[rr][cc] = *(const float4*)(Qb + (size_t)(q0 + rr) * HDIM + h * HD + cc);
  }

  float m = -1e30f, lsum = 0.f;
  float4 a0 = make_float4(0, 0, 0, 0), a1 = a0, a2 = a0, a3 = a0;

  int kend = q0 + 32;
  for (int kt = 0; kt < kend; kt += 32) {
    __syncthreads();  // protect Ks/Vs/Ss from previous iteration (and Qs on iter 0)
    for (int l = tid; l < 1024; l += 256) {
      int rr = l >> 5, cc = (l & 31) << 2;
      *(float4*)&Ks[rr][cc] = *(const float4*)(Kb + (size_t)(kt + rr) * 512 + hk * HD + cc);
      *(float4*)&Vs[rr][cc] = *(const float4*)(Vb + (size_t)(kt + rr) * 512 + hk * HD + cc);
    }
    __syncthreads();

    float dot[4] = {0.f, 0.f, 0.f, 0.f};
#pragma unroll
    for (int k4 = 0; k4 < HD; k4 += 4) {
      float4 qv = *(float4*)&Qs[r][k4];
#pragma unroll
      for (int j = 0; j < 4; j++) {
        float4 kv = *(float4*)&Ks[cb + 8 * j][k4];
        dot[j] = fmaf(qv.x, kv.x, dot[j]);
        dot[j] = fmaf(qv.y, kv.y, dot[j]);
        dot[j] = fmaf(qv.z, kv.z, dot[j]);
        dot[j] = fmaf(qv.w, kv.w, dot[j]);
      }
    }
    float sv[4];
    int gq = q0 + r;
#pragma unroll
    for (int j = 0; j < 4; j++) {
      int gk = kt + cb + 8 * j;
      sv[j] = dot[j] * ATT_SCALE + ((gk > gq) ? -1e9f : 0.f);
      Ss[r][cb + 8 * j] = sv[j];
    }
    __syncthreads();

    float tmax = -1e30f;
#pragma unroll
    for (int c = 0; c < 32; c++) tmax = fmaxf(tmax, Ss[r][c]);
    float mnew = fmaxf(m, tmax);
    float corr = __expf(m - mnew);
#pragma unroll
    for (int j = 0; j < 4; j++) Ss[r][cb + 8 * j] = __expf(sv[j] - mnew);
    m = mnew;
    __syncthreads();

    float rsum = 0.f;
#pragma unroll
    for (int c = 0; c < 32; c++) rsum += Ss[r][c];
    lsum = lsum * corr + rsum;
    a0.x *= corr; a0.y *= corr; a0.z *= corr; a0.w *= corr;
    a1.x *= corr; a1.y *= corr; a1.z *= corr; a1.w *= corr;
    a2.x *= corr; a2.y *= corr; a2.z *= corr; a2.w *= corr;
    a3.x *= corr; a3.y *= corr; a3.z *= corr; a3.w *= corr;
#pragma unroll
    for (int c = 0; c < 32; c++) {
      float p = Ss[r][c];
      float4 v0 = *(float4*)&Vs[c][cb * 4];
      float4 v1 = *(float4*)&Vs[c][cb * 4 + 32];
      float4 v2 = *(float4*)&Vs[c][cb * 4 + 64];
      float4 v3 = *(float4*)&Vs[c][cb * 4 + 96];
      a0.x = fmaf(p, v0.x, a0.x); a0.y = fmaf(p, v0.y, a0.y);
      a0.z = fmaf(p, v0.z, a0.z); a0.w = fmaf(p, v0.w, a0.w);
      a1.x = fmaf(p, v1.x, a1.x); a1.y = fmaf(p, v1.y, a1.y);
      a1.z = fmaf(p, v1.z, a1.z); a1.w = fmaf(p, v1.w, a1.w);
      a2.x = fmaf(p, v2.x, a2.x); a2.y = fmaf(p, v2.y, a2.y);
      a2.z = fmaf(p, v2.z, a2.z); a2.w = fmaf(p, v2.w, a2.w);
      a3.x = fmaf(p, v3.x, a3.x); a3.y = fmaf(p, v3.y, a3.y);
      a3.z = fmaf(p, v3.z, a3.z); a3.w = fmaf(p, v3.w, a3.w);
    }
  }
  float inv = 1.0f / lsum;
  float* op = AO + (size_t)(q0 + r) * HDIM + h * HD + cb * 4;
  float4 o;
  o.x = a0.x * inv; o.y = a0.y * inv; o.z = a0.z * inv; o.w = a0.w * inv; *(float4*)(op) = o;
  o.x = a1.x * inv; o.y = a1.y * inv; o.z = a1.z * inv; o.w = a1.w * inv; *(float4*)(op + 32) = o;
  o.x = a2.x * inv; o.y = a2.y * inv; o.z = a2.z * inv; o.w = a2.w * inv; *(float4*)(op + 64) = o;
  o.x = a3.x * inv; o.y = a3.y * inv; o.z = a3.z * inv; o.w = a3.w * inv; *(float4*)(op + 96) = o;
}

// ---------------------------------------------------------------- MoE routing
__global__ __launch_bounds__(256) void k_gate(
    const float* __restrict__ xn, const float* __restrict__ gw, float* __restrict__ logits) {
  int t = blockIdx.x;
  float a[8] = {0, 0, 0, 0, 0, 0, 0, 0};
#pragma unroll
  for (int i = 0; i < 8; i++) {
    int hh = threadIdx.x + i * 256;
    float xv = xn[(size_t)t * HDIM + hh];
    const float* gp = gw + (size_t)hh * 8;
    float4 g0 = *(const float4*)gp;
    float4 g1 = *(const float4*)(gp + 4);
    a[0] = fmaf(xv, g0.x, a[0]); a[1] = fmaf(xv, g0.y, a[1]);
    a[2] = fmaf(xv, g0.z, a[2]); a[3] = fmaf(xv, g0.w, a[3]);
    a[4] = fmaf(xv, g1.x, a[4]); a[5] = fmaf(xv, g1.y, a[5]);
    a[6] = fmaf(xv, g1.z, a[6]); a[7] = fmaf(xv, g1.w, a[7]);
  }
#pragma unroll
  for (int e = 0; e < 8; e++)
#pragma unroll
    for (int off = 32; off > 0; off >>= 1) a[e] += __shfl_down(a[e], off, 64);
  __shared__ float red[4][8];
  int lane = threadIdx.x & 63, wid = threadIdx.x >> 6;
  if (lane == 0) {
#pragma unroll
    for (int e = 0; e < 8; e++) red[wid][e] = a[e];
  }
  __syncthreads();
  if (threadIdx.x < 8) {
    int e = threadIdx.x;
    logits[(size_t)t * 8 + e] = red[0][e] + red[1][e] + red[2][e] + red[3][e];
  }
}

__global__ __launch_bounds__(256) void k_route(
    const float* __restrict__ logits, const float* __restrict__ bias,
    int* __restrict__ counts, int* __restrict__ toke, float* __restrict__ tokrw) {
  int t = blockIdx.x * 256 + threadIdx.x;
  if (t >= SDIM) return;
  float s[8], bsc[8];
#pragma unroll
  for (int e = 0; e < 8; e++) {
    float lg = logits[(size_t)t * 8 + e];
    s[e] = 1.0f / (1.0f + expf(-lg));
    bsc[e] = s[e] + bias[e];
  }
  int i0 = 0;
#pragma unroll
  for (int e = 1; e < 8; e++) if (bsc[e] > bsc[i0]) i0 = e;  // strict >: lower idx wins ties
  int i1 = (i0 == 0) ? 1 : 0;
#pragma unroll
  for (int e = 0; e < 8; e++) if (e != i0 && bsc[e] > bsc[i1]) i1 = e;
  float r0 = s[i0], r1 = s[i1];
  float den = fmaxf(r0 + r1, 1e-12f);
  atomicAdd(&counts[i0], 1);
  atomicAdd(&counts[i1], 1);
  toke[t * 2] = i0; toke[t * 2 + 1] = i1;
  tokrw[t * 2] = r0 / den; tokrw[t * 2 + 1] = r1 / den;
}

__global__ void k_offsets(const int* __restrict__ counts, int* __restrict__ aoff) {
  if (threadIdx.x == 0 && blockIdx.x == 0) {
    int o = 0;
#pragma unroll
    for (int e = 0; e < 8; e++) { aoff[e] = o; o += (counts[e] + 127) & ~127; }
    aoff[8] = o;
  }
}

__global__ __launch_bounds__(256) void k_scatter(
    const int* __restrict__ toke, const float* __restrict__ tokrw,
    const int* __restrict__ aoff, int* __restrict__ cursor,
    int* __restrict__ perm, float* __restrict__ rwbuf, int* __restrict__ tokslot) {
  int t = blockIdx.x * 256 + threadIdx.x;
  if (t >= SDIM) return;
#pragma unroll
  for (int sl = 0; sl < 2; sl++) {
    int e = toke[t * 2 + sl];
    int pos = atomicAdd(&cursor[e], 1);
    int j = aoff[e] + pos;
    perm[j] = t;
    rwbuf[j] = tokrw[t * 2 + sl];
    tokslot[t * 2 + sl] = j;
  }
}

__global__ __launch_bounds__(256) void k_fadd(
    float* __restrict__ out, const float* __restrict__ Yb, const int* __restrict__ tokslot) {
  int t = blockIdx.x;
  int j0 = tokslot[t * 2], j1 = tokslot[t * 2 + 1];
  const float* y0 = Yb + (size_t)j0 * HDIM;
  const float* y1 = Yb + (size_t)j1 * HDIM;
  float* orow = out + (size_t)t * HDIM;
  for (int c = threadIdx.x * 4; c < HDIM; c += 1024) {
    float4 o = *(float4*)(orow + c);
    float4 p = *(const float4*)(y0 + c);
    float4 q = *(const float4*)(y1 + c);
    o.x += p.x + q.x; o.y += p.y + q.y; o.z += p.z + q.z; o.w += p.w + q.w;
    *(float4*)(orow + c) = o;
  }
}

// ---------------------------------------------------------------- launch
extern "C" void kernel_launch(void* const* d_in, const int* in_sizes, int n_in,
                              void* d_out, int out_size, void* d_ws, size_t ws_size,
                              hipStream_t stream) {
  const float* hidden = (const float*)d_in[0];
  const float* cosb   = (const float*)d_in[2];
  const float* sinb   = (const float*)d_in[3];
  const float* ln1w   = (const float*)d_in[4];
  const float* ln2w   = (const float*)d_in[5];
  const float* wq     = (const float*)d_in[6];
  const float* wk     = (const float*)d_in[7];
  const float* wv     = (const float*)d_in[8];
  const float* wo     = (const float*)d_in[9];
  const float* qnw    = (const float*)d_in[10];
  const float* knw    = (const float*)d_in[11];
  const float* gatew  = (const float*)d_in[12];
  const float* biase  = (const float*)d_in[13];
  const float* w1     = (const float*)d_in[14];
  const float* w3     = (const float*)d_in[15];
  const float* w2     = (const float*)d_in[16];
  float* out = (float*)d_out;

  // workspace layout (floats); total ~122 MB
  float* ws = (float*)d_ws;
  size_t o = 0;
  float* xn = ws + o;     o += (size_t)SDIM * HDIM;      // 4M
  float* Qb = ws + o;     o += (size_t)SDIM * HDIM;      // 4M
  float* Kb = ws + o;     o += (size_t)SDIM * 512;       // 1M
  float* Vb = ws + o;     o += (size_t)SDIM * 512;       // 1M
  float* AO = ws + o;     o += (size_t)SDIM * HDIM;      // 4M
  float* Hb = ws + o;     o += (size_t)CAP * IDIM;       // 5.24M
  float* Yb = ws + o;     o += (size_t)CAP * HDIM;       // 10.5M
  float* logits = ws + o; o += (size_t)SDIM * 8;
  float* rwbuf = ws + o;  o += CAP;
  float* tokrw = ws + o;  o += (size_t)SDIM * 2;
  int* ibase = (int*)(ws + o);
  int* counts = ibase;          // 8
  int* cursor = ibase + 8;      // 8
  int* aoff = ibase + 16;       // 9 (pad to 12)
  int* perm = ibase + 28;       // CAP
  int* toke = perm + CAP;       // 2*SDIM
  int* tokslot = toke + 2 * SDIM;

  hipMemsetAsync(counts, 0, 16 * sizeof(int), stream);
  hipMemsetAsync(perm, 0xFF, CAP * sizeof(int), stream);

  // 1. ln1
  k_rmsnorm2048<<<SDIM, 256, 0, stream>>>(hidden, ln1w, xn);

  // 2. packed QKV
  GArgs ga = {};
  ga.A = xn; ga.lda = HDIM; ga.Kdim = HDIM;
  ga.Bq = wq; ga.Bk = wk; ga.Bv = wv;
  ga.Cq = Qb; ga.Ck = Kb; ga.Cv = Vb;
  k_gemm<0><<<dim3(24, 16), 256, 0, stream>>>(ga);

  // 3. q/k rmsnorm + rope
  k_qknorm_rope<<<SDIM, 256, 0, stream>>>(Qb, qnw, cosb, sinb, NHQ * HD);
  k_qknorm_rope<<<SDIM, 256, 0, stream>>>(Kb, knw, cosb, sinb, NKVH * HD);

  // 4. attention
  k_attn<<<dim3(SDIM / 32, NHQ), 256, 0, stream>>>(Qb, Kb, Vb, AO);

  // 5. wo + residual -> d_out
  GArgs g1 = {};
  g1.A = AO; g1.lda = HDIM; g1.B = wo; g1.ldb = HDIM;
  g1.C = out; g1.ldc = HDIM; g1.resid = hidden; g1.Kdim = HDIM;
  k_gemm<1><<<dim3(16, 16), 256, 0, stream>>>(g1);

  // 6. ln2
  k_rmsnorm2048<<<SDIM, 256, 0, stream>>>(out, ln2w, xn);

  // 7. routing
  k_gate<<<SDIM, 256, 0, stream>>>(xn, gatew, logits);
  k_route<<<8, 256, 0, stream>>>(logits, biase, counts, toke, tokrw);
  k_offsets<<<1, 64, 0, stream>>>(counts, aoff);
  k_scatter<<<8, 256, 0, stream>>>(toke, tokrw, aoff, cursor, perm, rwbuf, tokslot);

  // 8. grouped expert FFN
  GArgs g2 = {};
  g2.A = xn; g2.lda = HDIM; g2.B = w1; g2.B2 = w3; g2.ldb = IDIM;
  g2.C = Hb; g2.ldc = IDIM; g2.perm = perm; g2.aoff = aoff; g2.Kdim = HDIM;
  k_gemm<2><<<dim3(IDIM / 128, CAP / 128), 256, 0, stream>>>(g2);

  GArgs g3 = {};
  g3.A = Hb; g3.lda = IDIM; g3.B = w2; g3.ldb = HDIM;
  g3.C = Yb; g3.ldc = HDIM; g3.perm = perm; g3.rwbuf = rwbuf; g3.aoff = aoff; g3.Kdim = IDIM;
  k_gemm<3><<<dim3(HDIM / 128, CAP / 128), 256, 0, stream>>>(g3);

  // 9. final residual add
  k_fadd<<<SDIM, 256, 0, stream>>>(out, Yb, tokslot);
}

// Round 3
// 1374.845 us; speedup vs baseline: 2.0965x; 2.0965x over previous
//
#include <hip/hip_runtime.h>
#include <hip/hip_bf16.h>
#include <cstdint>

// MiniMax M2 decoder layer — round 2 resubmit: f16 MFMA GEMMs (fp32 accumulate).
// fp32 kept for: rmsnorms, q/k-norm+RoPE, attention, gate/routing, residuals.
// Weights are transpose-converted to [N][K] f16 planes each launch (B-frag of
// mfma_f32_16x16x32_f16 needs contiguous-k per lane). Activations written f16
// directly by producer epilogues.

#define SDIM 2048
#define HDIM 2048
#define NHQ 16
#define NKVH 4
#define HD 128
#define RDIM 64
#define IDIM 1024
#define CAP 5120
#define ATT_SCALE 0.08838834764831845f
#define EPS 1e-6f

typedef _Float16 f16x8 __attribute__((ext_vector_type(8)));
typedef _Float16 f16x4 __attribute__((ext_vector_type(4)));
typedef float f32x4 __attribute__((ext_vector_type(4)));

#define GLOAD16(g, l)                                                       \
  __builtin_amdgcn_global_load_lds(                                         \
      (const __attribute__((address_space(1))) void*)(g),                   \
      (__attribute__((address_space(3))) void*)(l), 16, 0, 0)

// ---------------------------------------------------------------- reductions
__device__ __forceinline__ float block_reduce_sum_256(float v) {
  __shared__ float sb[4];
#pragma unroll
  for (int off = 32; off > 0; off >>= 1) v += __shfl_down(v, off, 64);
  int lane = threadIdx.x & 63, wid = threadIdx.x >> 6;
  if (lane == 0) sb[wid] = v;
  __syncthreads();
  return sb[0] + sb[1] + sb[2] + sb[3];
}

// ---------------------------------------------------------------- rmsnorm H=2048 (fp32 in; optional fp32 out + f16 out)
__global__ __launch_bounds__(256) void k_rmsnorm(
    const float* __restrict__ x, const float* __restrict__ w,
    float* __restrict__ outf, _Float16* __restrict__ outh) {
  int row = blockIdx.x;
  const float* xr = x + (size_t)row * HDIM;
  int i0 = threadIdx.x * 4, i1 = i0 + 1024;
  float4 a = *(const float4*)(xr + i0);
  float4 b = *(const float4*)(xr + i1);
  float ss = a.x*a.x + a.y*a.y + a.z*a.z + a.w*a.w +
             b.x*b.x + b.y*b.y + b.z*b.z + b.w*b.w;
  float tot = block_reduce_sum_256(ss);
  float r = rsqrtf(tot * (1.0f / HDIM) + EPS);
  float4 wa = *(const float4*)(w + i0);
  float4 wb = *(const float4*)(w + i1);
  float4 oa, ob;
  oa.x = wa.x * (a.x * r); oa.y = wa.y * (a.y * r);
  oa.z = wa.z * (a.z * r); oa.w = wa.w * (a.w * r);
  ob.x = wb.x * (b.x * r); ob.y = wb.y * (b.y * r);
  ob.z = wb.z * (b.z * r); ob.w = wb.w * (b.w * r);
  if (outf) {
    *(float4*)(outf + (size_t)row * HDIM + i0) = oa;
    *(float4*)(outf + (size_t)row * HDIM + i1) = ob;
  }
  f16x4 ha, hb;
  ha[0] = (_Float16)oa.x; ha[1] = (_Float16)oa.y;
  ha[2] = (_Float16)oa.z; ha[3] = (_Float16)oa.w;
  hb[0] = (_Float16)ob.x; hb[1] = (_Float16)ob.y;
  hb[2] = (_Float16)ob.z; hb[3] = (_Float16)ob.w;
  *(f16x4*)(outh + (size_t)row * HDIM + i0) = ha;
  *(f16x4*)(outh + (size_t)row * HDIM + i1) = hb;
}

// ---------------------------------------------------------------- transpose+convert fp32 [R][C] -> f16 [C][R]
__global__ __launch_bounds__(256) void k_convT(
    const float* __restrict__ src, _Float16* __restrict__ dst,
    int R, int C, long srcZ, long dstZ) {
  __shared__ float T[64][65];
  src += (size_t)blockIdx.z * srcZ;
  dst += (size_t)blockIdx.z * dstZ;
  int r0 = blockIdx.y * 64, c0 = blockIdx.x * 64;
  int tr = threadIdx.x >> 2, tq = threadIdx.x & 3;
  const float* sp = src + (size_t)(r0 + tr) * C + c0 + tq * 16;
#pragma unroll
  for (int i = 0; i < 4; i++)
    *(float4*)&T[tr][tq * 16 + i * 4] = *(const float4*)(sp + i * 4);
  __syncthreads();
  int oc = threadIdx.x >> 2;  // output row = source col
  int h = threadIdx.x & 3;    // 16-wide k chunk
  _Float16* dp = dst + (size_t)(c0 + oc) * R + r0 + h * 16;
  f16x8 u0, u1;
#pragma unroll
  for (int j = 0; j < 8; j++) u0[j] = (_Float16)T[h * 16 + j][oc];
#pragma unroll
  for (int j = 0; j < 8; j++) u1[j] = (_Float16)T[h * 16 + 8 + j][oc];
  *(f16x8*)dp = u0;
  *((f16x8*)dp + 1) = u1;
}

// ---------------------------------------------------------------- q/k norm + rope (fp32, in place)
__global__ __launch_bounds__(256) void k_qknorm_rope(
    float* __restrict__ X, const float* __restrict__ w,
    const float* __restrict__ cosb, const float* __restrict__ sinb, int len) {
  int row = blockIdx.x;
  float* xr = X + (size_t)row * len;
  __shared__ float xs[HDIM];
  float ss = 0.f;
  for (int i = threadIdx.x * 4; i < len; i += 1024) {
    float4 v = *(const float4*)(xr + i);
    *(float4*)(xs + i) = v;
    ss += v.x*v.x + v.y*v.y + v.z*v.z + v.w*v.w;
  }
  float tot = block_reduce_sum_256(ss);
  float r = rsqrtf(tot / (float)len + EPS);
  const float* cr = cosb + (size_t)row * RDIM;
  const float* sr = sinb + (size_t)row * RDIM;
  for (int i = threadIdx.x; i < len; i += 256) {
    int d = i & (HD - 1);
    float xv = xs[i] * r * w[i];
    float o;
    if (d < RDIM) {
      float c = cr[d], s = sr[d];
      if (d < RDIM / 2) {
        float pn = xs[i + RDIM / 2] * r * w[i + RDIM / 2];
        o = xv * c - pn * s;
      } else {
        float pn = xs[i - RDIM / 2] * r * w[i - RDIM / 2];
        o = xv * c + pn * s;
      }
    } else {
      o = xv;
    }
    xr[i] = o;
  }
}

// ---------------------------------------------------------------- MFMA GEMM
// A: f16 [M][K] (MODE2: rows gathered via perm). Bt: f16 [N][K].
// MODE 0: QKV packed outputs (fp32). MODE 1: out = A@B + resid (fp32).
// MODE 2: G = A@B (f16, grouped experts). MODE 3: Yb = (A@B)*rw (fp32, grouped).
struct MArgs {
  const _Float16* A;
  const _Float16* Bt;
  int Kdim;
  float* Cq; float* Ck; float* Cv;   // mode 0
  float* C;                          // mode 1 / 3
  const float* resid;                // mode 1
  _Float16* Ch;                      // mode 2
  const int* perm; const int* aoff; const float* rwbuf;
};

template <int MODE>
__global__ __launch_bounds__(256) void k_mfma(MArgs g) {
  __shared__ _Float16 Ah[128 * 32];
  __shared__ _Float16 Bh[128 * 32];
  int tid = threadIdx.x;
  int lane = tid & 63, w = tid >> 6;
  int wr = w >> 1, wc = w & 1;
  int m0 = blockIdx.y * 128;
  int n0 = blockIdx.x * 128;
  int K = g.Kdim;

  const _Float16* Bt = g.Bt;
  if (MODE >= 2) {
    if (m0 >= g.aoff[8]) return;
    int expert = 0;
    while (g.aoff[expert + 1] <= m0) expert++;
    Bt += (size_t)expert * (size_t)((MODE == 2) ? 2048 * 2048 : 2048 * 1024);
  }

  // staging addresses: wave w owns chunks {w, w+4} of A and of B (16 rows each)
  int crow = lane >> 2;           // row within chunk
  int ccol = (lane & 3) * 8;      // k offset (halves)
  int r0 = m0 + w * 16 + crow, r1 = m0 + (w + 4) * 16 + crow;
  if (MODE == 2) {
    int p0 = g.perm[r0], p1 = g.perm[r1];
    r0 = (p0 < 0) ? 0 : p0;
    r1 = (p1 < 0) ? 0 : p1;
  }
  const _Float16* aSrc0 = g.A + (size_t)r0 * K + ccol;
  const _Float16* aSrc1 = g.A + (size_t)r1 * K + ccol;
  const _Float16* bSrc0 = Bt + (size_t)(n0 + w * 16 + crow) * K + ccol;
  const _Float16* bSrc1 = Bt + (size_t)(n0 + (w + 4) * 16 + crow) * K + ccol;
  _Float16* aDst0 = &Ah[w * 512];
  _Float16* aDst1 = &Ah[(w + 4) * 512];
  _Float16* bDst0 = &Bh[w * 512];
  _Float16* bDst1 = &Bh[(w + 4) * 512];

  int fr = lane & 15;
  int kb = (lane >> 4) * 8;
  const _Float16* aBase = &Ah[(wr * 64 + fr) * 32 + kb];
  const _Float16* bBase = &Bh[(wc * 64 + fr) * 32 + kb];

  f32x4 acc[4][4] = {};

  for (int k0 = 0; k0 < K; k0 += 32) {
    GLOAD16(aSrc0, aDst0);
    GLOAD16(aSrc1, aDst1);
    GLOAD16(bSrc0, bDst0);
    GLOAD16(bSrc1, bDst1);
    __syncthreads();

    f16x8 av[4], bv[4];
#pragma unroll
    for (int m = 0; m < 4; m++) av[m] = *(const f16x8*)(aBase + m * 512);
#pragma unroll
    for (int n = 0; n < 4; n++) bv[n] = *(const f16x8*)(bBase + n * 512);
#pragma unroll
    for (int m = 0; m < 4; m++)
#pragma unroll
      for (int n = 0; n < 4; n++)
        acc[m][n] = __builtin_amdgcn_mfma_f32_16x16x32_f16(av[m], bv[n], acc[m][n], 0, 0, 0);
    __syncthreads();

    aSrc0 += 32; aSrc1 += 32; bSrc0 += 32; bSrc1 += 32;
  }

  // epilogue
  float* Cw = nullptr; int ldc = 2048, cb0 = 0;
  if (MODE == 0) {
    int nt = blockIdx.x;
    if (nt < 16)      { Cw = g.Cq; ldc = 2048; cb0 = 0; }
    else if (nt < 20) { Cw = g.Ck; ldc = 512;  cb0 = 2048; }
    else              { Cw = g.Cv; ldc = 512;  cb0 = 2560; }
  }
  int rbase = (lane >> 4) * 4;
#pragma unroll
  for (int m = 0; m < 4; m++) {
#pragma unroll
    for (int r = 0; r < 4; r++) {
      int gr = m0 + wr * 64 + m * 16 + rbase + r;
      int tok = 0; float sc = 0.f;
      if (MODE == 3) {
        tok = g.perm[gr];
        sc = g.rwbuf[gr];
      }
#pragma unroll
      for (int n = 0; n < 4; n++) {
        int gc = n0 + wc * 64 + n * 16 + fr;
        float v = acc[m][n][r];
        if (MODE == 0) {
          Cw[(size_t)gr * ldc + (gc - cb0)] = v;
        } else if (MODE == 1) {
          g.C[(size_t)gr * 2048 + gc] = v + g.resid[(size_t)gr * 2048 + gc];
        } else if (MODE == 2) {
          g.Ch[(size_t)gr * 2048 + gc] = (_Float16)v;
        } else {
          if (tok >= 0) g.C[(size_t)gr * 2048 + gc] = v * sc;
        }
      }
    }
  }
}

// ---------------------------------------------------------------- flash attention (fp32, f16 out)
__global__ __launch_bounds__(256) void k_attn(
    const float* __restrict__ Qb, const float* __restrict__ Kb,
    const float* __restrict__ Vb, _Float16* __restrict__ AO) {
  __shared__ float Qs[32][132];
  __shared__ float Ks[32][132];
  __shared__ float Vs[32][132];
  __shared__ float Ss[32][36];
  int h = blockIdx.y;
  int q0 = blockIdx.x * 32;
  int hk = h >> 2;
  int tid = threadIdx.x;
  int r = tid >> 3;
  int cb = tid & 7;

  for (int l = tid; l < 1024; l += 256) {
    int rr = l >> 5, cc = (l & 31) << 2;
    *(float4*)&Qs[rr][cc] = *(const float4*)(Qb + (size_t)(q0 + rr) * HDIM + h * HD + cc);
  }

  float m = -1e30f, lsum = 0.f;
  float4 a0 = make_float4(0, 0, 0, 0), a1 = a0, a2 = a0, a3 = a0;

  int kend = q0 + 32;
  for (int kt = 0; kt < kend; kt += 32) {
    __syncthreads();
    for (int l = tid; l < 1024; l += 256) {
      int rr = l >> 5, cc = (l & 31) << 2;
      *(float4*)&Ks[rr][cc] = *(const float4*)(Kb + (size_t)(kt + rr) * 512 + hk * HD + cc);
      *(float4*)&Vs[rr][cc] = *(const float4*)(Vb + (size_t)(kt + rr) * 512 + hk * HD + cc);
    }
    __syncthreads();

    float dot[4] = {0.f, 0.f, 0.f, 0.f};
#pragma unroll
    for (int k4 = 0; k4 < HD; k4 += 4) {
      float4 qv = *(float4*)&Qs[r][k4];
#pragma unroll
      for (int j = 0; j < 4; j++) {
        float4 kv = *(float4*)&Ks[cb + 8 * j][k4];
        dot[j] = fmaf(qv.x, kv.x, dot[j]);
        dot[j] = fmaf(qv.y, kv.y, dot[j]);
        dot[j] = fmaf(qv.z, kv.z, dot[j]);
        dot[j] = fmaf(qv.w, kv.w, dot[j]);
      }
    }
    float sv[4];
    int gq = q0 + r;
#pragma unroll
    for (int j = 0; j < 4; j++) {
      int gk = kt + cb + 8 * j;
      sv[j] = dot[j] * ATT_SCALE + ((gk > gq) ? -1e9f : 0.f);
      Ss[r][cb + 8 * j] = sv[j];
    }
    __syncthreads();

    float tmax = -1e30f;
#pragma unroll
    for (int c = 0; c < 32; c++) tmax = fmaxf(tmax, Ss[r][c]);
    float mnew = fmaxf(m, tmax);
    float corr = __expf(m - mnew);
#pragma unroll
    for (int j = 0; j < 4; j++) Ss[r][cb + 8 * j] = __expf(sv[j] - mnew);
    m = mnew;
    __syncthreads();

    float rsum = 0.f;
#pragma unroll
    for (int c = 0; c < 32; c++) rsum += Ss[r][c];
    lsum = lsum * corr + rsum;
    a0.x *= corr; a0.y *= corr; a0.z *= corr; a0.w *= corr;
    a1.x *= corr; a1.y *= corr; a1.z *= corr; a1.w *= corr;
    a2.x *= corr; a2.y *= corr; a2.z *= corr; a2.w *= corr;
    a3.x *= corr; a3.y *= corr; a3.z *= corr; a3.w *= corr;
#pragma unroll
    for (int c = 0; c < 32; c++) {
      float p = Ss[r][c];
      float4 v0 = *(float4*)&Vs[c][cb * 4];
      float4 v1 = *(float4*)&Vs[c][cb * 4 + 32];
      float4 v2 = *(float4*)&Vs[c][cb * 4 + 64];
      float4 v3 = *(float4*)&Vs[c][cb * 4 + 96];
      a0.x = fmaf(p, v0.x, a0.x); a0.y = fmaf(p, v0.y, a0.y);
      a0.z = fmaf(p, v0.z, a0.z); a0.w = fmaf(p, v0.w, a0.w);
      a1.x = fmaf(p, v1.x, a1.x); a1.y = fmaf(p, v1.y, a1.y);
      a1.z = fmaf(p, v1.z, a1.z); a1.w = fmaf(p, v1.w, a1.w);
      a2.x = fmaf(p, v2.x, a2.x); a2.y = fmaf(p, v2.y, a2.y);
      a2.z = fmaf(p, v2.z, a2.z); a2.w = fmaf(p, v2.w, a2.w);
      a3.x = fmaf(p, v3.x, a3.x); a3.y = fmaf(p, v3.y, a3.y);
      a3.z = fmaf(p, v3.z, a3.z); a3.w = fmaf(p, v3.w, a3.w);
    }
  }
  float inv = 1.0f / lsum;
  _Float16* op = AO + (size_t)(q0 + r) * HDIM + h * HD + cb * 4;
  f16x4 o;
  o[0] = (_Float16)(a0.x * inv); o[1] = (_Float16)(a0.y * inv);
  o[2] = (_Float16)(a0.z * inv); o[3] = (_Float16)(a0.w * inv);
  *(f16x4*)(op) = o;
  o[0] = (_Float16)(a1.x * inv); o[1] = (_Float16)(a1.y * inv);
  o[2] = (_Float16)(a1.z * inv); o[3] = (_Float16)(a1.w * inv);
  *(f16x4*)(op + 32) = o;
  o[0] = (_Float16)(a2.x * inv); o[1] = (_Float16)(a2.y * inv);
  o[2] = (_Float16)(a2.z * inv); o[3] = (_Float16)(a2.w * inv);
  *(f16x4*)(op + 64) = o;
  o[0] = (_Float16)(a3.x * inv); o[1] = (_Float16)(a3.y * inv);
  o[2] = (_Float16)(a3.z * inv); o[3] = (_Float16)(a3.w * inv);
  *(f16x4*)(op + 96) = o;
}

// ---------------------------------------------------------------- MoE routing (fp32, unchanged)
__global__ __launch_bounds__(256) void k_gate(
    const float* __restrict__ xn, const float* __restrict__ gw, float* __restrict__ logits) {
  int t = blockIdx.x;
  float a[8] = {0, 0, 0, 0, 0, 0, 0, 0};
#pragma unroll
  for (int i = 0; i < 8; i++) {
    int hh = threadIdx.x + i * 256;
    float xv = xn[(size_t)t * HDIM + hh];
    const float* gp = gw + (size_t)hh * 8;
    float4 g0 = *(const float4*)gp;
    float4 g1 = *(const float4*)(gp + 4);
    a[0] = fmaf(xv, g0.x, a[0]); a[1] = fmaf(xv, g0.y, a[1]);
    a[2] = fmaf(xv, g0.z, a[2]); a[3] = fmaf(xv, g0.w, a[3]);
    a[4] = fmaf(xv, g1.x, a[4]); a[5] = fmaf(xv, g1.y, a[5]);
    a[6] = fmaf(xv, g1.z, a[6]); a[7] = fmaf(xv, g1.w, a[7]);
  }
#pragma unroll
  for (int e = 0; e < 8; e++)
#pragma unroll
    for (int off = 32; off > 0; off >>= 1) a[e] += __shfl_down(a[e], off, 64);
  __shared__ float red[4][8];
  int lane = threadIdx.x & 63, wid = threadIdx.x >> 6;
  if (lane == 0) {
#pragma unroll
    for (int e = 0; e < 8; e++) red[wid][e] = a[e];
  }
  __syncthreads();
  if (threadIdx.x < 8) {
    int e = threadIdx.x;
    logits[(size_t)t * 8 + e] = red[0][e] + red[1][e] + red[2][e] + red[3][e];
  }
}

__global__ __launch_bounds__(256) void k_route(
    const float* __restrict__ logits, const float* __restrict__ bias,
    int* __restrict__ counts, int* __restrict__ toke, float* __restrict__ tokrw) {
  int t = blockIdx.x * 256 + threadIdx.x;
  if (t >= SDIM) return;
  float s[8], bsc[8];
#pragma unroll
  for (int e = 0; e < 8; e++) {
    float lg = logits[(size_t)t * 8 + e];
    s[e] = 1.0f / (1.0f + expf(-lg));
    bsc[e] = s[e] + bias[e];
  }
  int i0 = 0;
#pragma unroll
  for (int e = 1; e < 8; e++) if (bsc[e] > bsc[i0]) i0 = e;
  int i1 = (i0 == 0) ? 1 : 0;
#pragma unroll
  for (int e = 0; e < 8; e++) if (e != i0 && bsc[e] > bsc[i1]) i1 = e;
  float r0 = s[i0], r1 = s[i1];
  float den = fmaxf(r0 + r1, 1e-12f);
  atomicAdd(&counts[i0], 1);
  atomicAdd(&counts[i1], 1);
  toke[t * 2] = i0; toke[t * 2 + 1] = i1;
  tokrw[t * 2] = r0 / den; tokrw[t * 2 + 1] = r1 / den;
}

__global__ void k_offsets(const int* __restrict__ counts, int* __restrict__ aoff) {
  if (threadIdx.x == 0 && blockIdx.x == 0) {
    int o = 0;
#pragma unroll
    for (int e = 0; e < 8; e++) { aoff[e] = o; o += (counts[e] + 127) & ~127; }
    aoff[8] = o;
  }
}

__global__ __launch_bounds__(256) void k_scatter(
    const int* __restrict__ toke, const float* __restrict__ tokrw,
    const int* __restrict__ aoff, int* __restrict__ cursor,
    int* __restrict__ perm, float* __restrict__ rwbuf, int* __restrict__ tokslot) {
  int t = blockIdx.x * 256 + threadIdx.x;
  if (t >= SDIM) return;
#pragma unroll
  for (int sl = 0; sl < 2; sl++) {
    int e = toke[t * 2 + sl];
    int pos = atomicAdd(&cursor[e], 1);
    int j = aoff[e] + pos;
    perm[j] = t;
    rwbuf[j] = tokrw[t * 2 + sl];
    tokslot[t * 2 + sl] = j;
  }
}

// ---------------------------------------------------------------- silu(g)*u -> Hb (f16), zero padding rows
__global__ __launch_bounds__(128) void k_silu(
    const _Float16* __restrict__ G, const int* __restrict__ perm,
    _Float16* __restrict__ Hb) {
  int j = blockIdx.x;
  int c = threadIdx.x;
  f16x8 o;
  if (perm[j] < 0) {
#pragma unroll
    for (int t = 0; t < 8; t++) o[t] = (_Float16)0.f;
  } else {
    f16x8 g8 = *(const f16x8*)(G + (size_t)j * 2048 + c * 8);
    f16x8 u8 = *(const f16x8*)(G + (size_t)j * 2048 + 1024 + c * 8);
#pragma unroll
    for (int t = 0; t < 8; t++) {
      float gv = (float)g8[t], uv = (float)u8[t];
      o[t] = (_Float16)(gv / (1.0f + expf(-gv)) * uv);
    }
  }
  *(f16x8*)(Hb + (size_t)j * 1024 + c * 8) = o;
}

__global__ __launch_bounds__(256) void k_fadd(
    float* __restrict__ out, const float* __restrict__ Yb, const int* __restrict__ tokslot) {
  int t = blockIdx.x;
  int j0 = tokslot[t * 2], j1 = tokslot[t * 2 + 1];
  const float* y0 = Yb + (size_t)j0 * HDIM;
  const float* y1 = Yb + (size_t)j1 * HDIM;
  float* orow = out + (size_t)t * HDIM;
  for (int c = threadIdx.x * 4; c < HDIM; c += 1024) {
    float4 o = *(float4*)(orow + c);
    float4 p = *(const float4*)(y0 + c);
    float4 q = *(const float4*)(y1 + c);
    o.x += p.x + q.x; o.y += p.y + q.y; o.z += p.z + q.z; o.w += p.w + q.w;
    *(float4*)(orow + c) = o;
  }
}

// ---------------------------------------------------------------- launch
extern "C" void kernel_launch(void* const* d_in, const int* in_sizes, int n_in,
                              void* d_out, int out_size, void* d_ws, size_t ws_size,
                              hipStream_t stream) {
  const float* hidden = (const float*)d_in[0];
  const float* cosb   = (const float*)d_in[2];
  const float* sinb   = (const float*)d_in[3];
  const float* ln1w   = (const float*)d_in[4];
  const float* ln2w   = (const float*)d_in[5];
  const float* wq     = (const float*)d_in[6];
  const float* wk     = (const float*)d_in[7];
  const float* wv     = (const float*)d_in[8];
  const float* wo     = (const float*)d_in[9];
  const float* qnw    = (const float*)d_in[10];
  const float* knw    = (const float*)d_in[11];
  const float* gatew  = (const float*)d_in[12];
  const float* biase  = (const float*)d_in[13];
  const float* w1     = (const float*)d_in[14];
  const float* w3     = (const float*)d_in[15];
  const float* w2     = (const float*)d_in[16];
  float* out = (float*)d_out;

  // ---- workspace carve-up (bytes, 256B aligned); total ~262 MB
  char* base = (char*)d_ws;
  size_t off = 0;
  auto alloc = [&](size_t bytes) {
    void* p = base + off;
    off = (off + bytes + 255) & ~(size_t)255;
    return p;
  };
  _Float16* xnh  = (_Float16*)alloc((size_t)SDIM * HDIM * 2);
  float* Qb      = (float*)alloc((size_t)SDIM * HDIM * 4);
  float* Kb      = (float*)alloc((size_t)SDIM * 512 * 4);
  float* Vb      = (float*)alloc((size_t)SDIM * 512 * 4);
  _Float16* AOh  = (_Float16*)alloc((size_t)SDIM * HDIM * 2);
  float* xn2     = (float*)alloc((size_t)SDIM * HDIM * 4);
  _Float16* xn2h = (_Float16*)alloc((size_t)SDIM * HDIM * 2);
  _Float16* Gbuf = (_Float16*)alloc((size_t)CAP * 2048 * 2);
  _Float16* Hbh  = (_Float16*)alloc((size_t)CAP * IDIM * 2);
  float* Yb      = (float*)alloc((size_t)CAP * HDIM * 4);
  _Float16* qkvt = (_Float16*)alloc((size_t)3072 * 2048 * 2);
  _Float16* wot  = (_Float16*)alloc((size_t)2048 * 2048 * 2);
  _Float16* w13t = (_Float16*)alloc((size_t)8 * 2048 * 2048 * 2);
  _Float16* w2t  = (_Float16*)alloc((size_t)8 * 2048 * 1024 * 2);
  float* logits  = (float*)alloc((size_t)SDIM * 8 * 4);
  float* rwbuf   = (float*)alloc((size_t)CAP * 4);
  float* tokrw   = (float*)alloc((size_t)SDIM * 2 * 4);
  int* counts    = (int*)alloc(16 * 4);
  int* aoff      = (int*)alloc(12 * 4);
  int* perm      = (int*)alloc((size_t)CAP * 4);
  int* toke      = (int*)alloc((size_t)SDIM * 2 * 4);
  int* tokslot   = (int*)alloc((size_t)SDIM * 2 * 4);
  int* cursor    = counts + 8;

  hipMemsetAsync(counts, 0, 16 * sizeof(int), stream);
  hipMemsetAsync(perm, 0xFF, CAP * sizeof(int), stream);

  // ---- weight transpose+convert to f16 [N][K]
  // qkvt rows: [0,2048)=wq^T, [2048,2560)=wk^T, [2560,3072)=wv^T
  k_convT<<<dim3(32, 32, 1), 256, 0, stream>>>(wq, qkvt, 2048, 2048, 0, 0);
  k_convT<<<dim3(8, 32, 1), 256, 0, stream>>>(wk, qkvt + (size_t)2048 * 2048, 2048, 512, 0, 0);
  k_convT<<<dim3(8, 32, 1), 256, 0, stream>>>(wv, qkvt + (size_t)2560 * 2048, 2048, 512, 0, 0);
  k_convT<<<dim3(32, 32, 1), 256, 0, stream>>>(wo, wot, 2048, 2048, 0, 0);
  // w13t per expert: rows [0,1024)=w1_e^T, [1024,2048)=w3_e^T
  k_convT<<<dim3(16, 32, 8), 256, 0, stream>>>(w1, w13t, 2048, 1024,
                                               (long)2048 * 1024, (long)2048 * 2048);
  k_convT<<<dim3(16, 32, 8), 256, 0, stream>>>(w3, w13t + (size_t)1024 * 2048, 2048, 1024,
                                               (long)2048 * 1024, (long)2048 * 2048);
  k_convT<<<dim3(32, 16, 8), 256, 0, stream>>>(w2, w2t, 1024, 2048,
                                               (long)1024 * 2048, (long)2048 * 1024);

  // 1. ln1 -> xnh (f16 only)
  k_rmsnorm<<<SDIM, 256, 0, stream>>>(hidden, ln1w, nullptr, xnh);

  // 2. QKV MFMA
  MArgs a0 = {};
  a0.A = xnh; a0.Bt = qkvt; a0.Kdim = HDIM;
  a0.Cq = Qb; a0.Ck = Kb; a0.Cv = Vb;
  k_mfma<0><<<dim3(24, 16), 256, 0, stream>>>(a0);

  // 3. q/k rmsnorm + rope (fp32)
  k_qknorm_rope<<<SDIM, 256, 0, stream>>>(Qb, qnw, cosb, sinb, NHQ * HD);
  k_qknorm_rope<<<SDIM, 256, 0, stream>>>(Kb, knw, cosb, sinb, NKVH * HD);

  // 4. attention (fp32 compute, f16 out)
  k_attn<<<dim3(SDIM / 32, NHQ), 256, 0, stream>>>(Qb, Kb, Vb, AOh);

  // 5. wo + residual -> out
  MArgs a1 = {};
  a1.A = AOh; a1.Bt = wot; a1.Kdim = HDIM; a1.C = out; a1.resid = hidden;
  k_mfma<1><<<dim3(16, 16), 256, 0, stream>>>(a1);

  // 6. ln2 -> xn2 (fp32 for gate) + xn2h (f16 for MoE)
  k_rmsnorm<<<SDIM, 256, 0, stream>>>(out, ln2w, xn2, xn2h);

  // 7. routing
  k_gate<<<SDIM, 256, 0, stream>>>(xn2, gatew, logits);
  k_route<<<8, 256, 0, stream>>>(logits, biase, counts, toke, tokrw);
  k_offsets<<<1, 64, 0, stream>>>(counts, aoff);
  k_scatter<<<8, 256, 0, stream>>>(toke, tokrw, aoff, cursor, perm, rwbuf, tokslot);

  // 8. MoE up: G = gather(xn2h) @ [w1|w3]^T  (f16 out)
  MArgs a2 = {};
  a2.A = xn2h; a2.Bt = w13t; a2.Kdim = HDIM; a2.Ch = Gbuf;
  a2.perm = perm; a2.aoff = aoff;
  k_mfma<2><<<dim3(16, CAP / 128), 256, 0, stream>>>(a2);

  k_silu<<<CAP, 128, 0, stream>>>(Gbuf, perm, Hbh);

  // 9. MoE down: Yb = (Hb @ w2^T) * rw
  MArgs a3 = {};
  a3.A = Hbh; a3.Bt = w2t; a3.Kdim = IDIM; a3.C = Yb;
  a3.perm = perm; a3.aoff = aoff; a3.rwbuf = rwbuf;
  k_mfma<3><<<dim3(16, CAP / 128), 256, 0, stream>>>(a3);

  // 10. final residual add
  k_fadd<<<SDIM, 256, 0, stream>>>(out, Yb, tokslot);
}

// Round 8
// 751.884 us; speedup vs baseline: 3.8334x; 1.8285x over previous
//
#include <hip/hip_runtime.h>
#include <hip/hip_bf16.h>
#include <cstdint>

// MiniMax M2 decoder layer — round 7 resubmit: f16 MFMA GEMMs + f16 MFMA flash attention.
// fp32 kept for: rmsnorms, q/k-norm+RoPE, softmax stats, gate/routing, residuals.

#define SDIM 2048
#define HDIM 2048
#define NHQ 16
#define NKVH 4
#define HD 128
#define RDIM 64
#define IDIM 1024
#define CAP 5120
#define ATT_SCALE 0.08838834764831845f
#define EPS 1e-6f

typedef _Float16 f16x8 __attribute__((ext_vector_type(8)));
typedef _Float16 f16x4 __attribute__((ext_vector_type(4)));
typedef float f32x4 __attribute__((ext_vector_type(4)));

#define GLOAD16(g, l)                                                       \
  __builtin_amdgcn_global_load_lds(                                         \
      (const __attribute__((address_space(1))) void*)(g),                   \
      (__attribute__((address_space(3))) void*)(l), 16, 0, 0)

// ---------------------------------------------------------------- reductions
__device__ __forceinline__ float block_reduce_sum_256(float v) {
  __shared__ float sb[4];
#pragma unroll
  for (int off = 32; off > 0; off >>= 1) v += __shfl_down(v, off, 64);
  int lane = threadIdx.x & 63, wid = threadIdx.x >> 6;
  if (lane == 0) sb[wid] = v;
  __syncthreads();
  return sb[0] + sb[1] + sb[2] + sb[3];
}

// ---------------------------------------------------------------- rmsnorm H=2048
__global__ __launch_bounds__(256) void k_rmsnorm(
    const float* __restrict__ x, const float* __restrict__ w,
    float* __restrict__ outf, _Float16* __restrict__ outh) {
  int row = blockIdx.x;
  const float* xr = x + (size_t)row * HDIM;
  int i0 = threadIdx.x * 4, i1 = i0 + 1024;
  float4 a = *(const float4*)(xr + i0);
  float4 b = *(const float4*)(xr + i1);
  float ss = a.x*a.x + a.y*a.y + a.z*a.z + a.w*a.w +
             b.x*b.x + b.y*b.y + b.z*b.z + b.w*b.w;
  float tot = block_reduce_sum_256(ss);
  float r = rsqrtf(tot * (1.0f / HDIM) + EPS);
  float4 wa = *(const float4*)(w + i0);
  float4 wb = *(const float4*)(w + i1);
  float4 oa, ob;
  oa.x = wa.x * (a.x * r); oa.y = wa.y * (a.y * r);
  oa.z = wa.z * (a.z * r); oa.w = wa.w * (a.w * r);
  ob.x = wb.x * (b.x * r); ob.y = wb.y * (b.y * r);
  ob.z = wb.z * (b.z * r); ob.w = wb.w * (b.w * r);
  if (outf) {
    *(float4*)(outf + (size_t)row * HDIM + i0) = oa;
    *(float4*)(outf + (size_t)row * HDIM + i1) = ob;
  }
  f16x4 ha, hb;
  ha[0] = (_Float16)oa.x; ha[1] = (_Float16)oa.y;
  ha[2] = (_Float16)oa.z; ha[3] = (_Float16)oa.w;
  hb[0] = (_Float16)ob.x; hb[1] = (_Float16)ob.y;
  hb[2] = (_Float16)ob.z; hb[3] = (_Float16)ob.w;
  *(f16x4*)(outh + (size_t)row * HDIM + i0) = ha;
  *(f16x4*)(outh + (size_t)row * HDIM + i1) = hb;
}

// ---------------------------------------------------------------- transpose+convert fp32 [R][C] -> f16 [C][R]
__global__ __launch_bounds__(256) void k_convT(
    const float* __restrict__ src, _Float16* __restrict__ dst,
    int R, int C, long srcZ, long dstZ) {
  __shared__ float T[64][65];
  src += (size_t)blockIdx.z * srcZ;
  dst += (size_t)blockIdx.z * dstZ;
  int r0 = blockIdx.y * 64, c0 = blockIdx.x * 64;
  int tr = threadIdx.x >> 2, tq = threadIdx.x & 3;
  const float* sp = src + (size_t)(r0 + tr) * C + c0 + tq * 16;
#pragma unroll
  for (int i = 0; i < 4; i++)
    *(float4*)&T[tr][tq * 16 + i * 4] = *(const float4*)(sp + i * 4);
  __syncthreads();
  int oc = threadIdx.x >> 2;  // output row = source col
  int h = threadIdx.x & 3;    // 16-wide k chunk
  _Float16* dp = dst + (size_t)(c0 + oc) * R + r0 + h * 16;
  f16x8 u0, u1;
#pragma unroll
  for (int j = 0; j < 8; j++) u0[j] = (_Float16)T[h * 16 + j][oc];
#pragma unroll
  for (int j = 0; j < 8; j++) u1[j] = (_Float16)T[h * 16 + 8 + j][oc];
  *(f16x8*)dp = u0;
  *((f16x8*)dp + 1) = u1;
}

// ---------------------------------------------------------------- q/k norm + rope (fp32 in, f16 out)
__global__ __launch_bounds__(256) void k_qknorm_rope(
    const float* __restrict__ X, const float* __restrict__ w,
    const float* __restrict__ cosb, const float* __restrict__ sinb, int len,
    _Float16* __restrict__ outh) {
  int row = blockIdx.x;
  const float* xr = X + (size_t)row * len;
  __shared__ float xs[HDIM];
  float ss = 0.f;
  for (int i = threadIdx.x * 4; i < len; i += 1024) {
    float4 v = *(const float4*)(xr + i);
    *(float4*)(xs + i) = v;
    ss += v.x*v.x + v.y*v.y + v.z*v.z + v.w*v.w;
  }
  float tot = block_reduce_sum_256(ss);
  float r = rsqrtf(tot / (float)len + EPS);
  const float* cr = cosb + (size_t)row * RDIM;
  const float* sr = sinb + (size_t)row * RDIM;
  _Float16* orow = outh + (size_t)row * len;
  for (int i = threadIdx.x; i < len; i += 256) {
    int d = i & (HD - 1);
    float xv = xs[i] * r * w[i];
    float o;
    if (d < RDIM) {
      float c = cr[d], s = sr[d];
      if (d < RDIM / 2) {
        float pn = xs[i + RDIM / 2] * r * w[i + RDIM / 2];
        o = xv * c - pn * s;
      } else {
        float pn = xs[i - RDIM / 2] * r * w[i - RDIM / 2];
        o = xv * c + pn * s;
      }
    } else {
      o = xv;
    }
    orow[i] = (_Float16)o;
  }
}

// ---------------------------------------------------------------- MFMA GEMM
// A: f16 [M][K] (MODE2: rows gathered via perm). Bt: f16 [N][K].
// MODE 0: QKV packed outputs (fp32). MODE 1: out = A@B + resid (fp32).
// MODE 2: G = A@B (f16, grouped experts). MODE 3: Yb = (A@B)*rw (fp32, grouped).
struct MArgs {
  const _Float16* A;
  const _Float16* Bt;
  int Kdim;
  float* Cq; float* Ck; float* Cv;   // mode 0
  float* C;                          // mode 1 / 3
  const float* resid;                // mode 1
  _Float16* Ch;                      // mode 2
  const int* perm; const int* aoff; const float* rwbuf;
};

template <int MODE>
__global__ __launch_bounds__(256) void k_mfma(MArgs g) {
  __shared__ _Float16 Ah[128 * 32];
  __shared__ _Float16 Bh[128 * 32];
  int tid = threadIdx.x;
  int lane = tid & 63, w = tid >> 6;
  int wr = w >> 1, wc = w & 1;
  int m0 = blockIdx.y * 128;
  int n0 = blockIdx.x * 128;
  int K = g.Kdim;

  const _Float16* Bt = g.Bt;
  if (MODE >= 2) {
    if (m0 >= g.aoff[8]) return;
    int expert = 0;
    while (g.aoff[expert + 1] <= m0) expert++;
    Bt += (size_t)expert * (size_t)((MODE == 2) ? 2048 * 2048 : 2048 * 1024);
  }

  int crow = lane >> 2;
  int ccol = (lane & 3) * 8;
  int r0 = m0 + w * 16 + crow, r1 = m0 + (w + 4) * 16 + crow;
  if (MODE == 2) {
    int p0 = g.perm[r0], p1 = g.perm[r1];
    r0 = (p0 < 0) ? 0 : p0;
    r1 = (p1 < 0) ? 0 : p1;
  }
  const _Float16* aSrc0 = g.A + (size_t)r0 * K + ccol;
  const _Float16* aSrc1 = g.A + (size_t)r1 * K + ccol;
  const _Float16* bSrc0 = Bt + (size_t)(n0 + w * 16 + crow) * K + ccol;
  const _Float16* bSrc1 = Bt + (size_t)(n0 + (w + 4) * 16 + crow) * K + ccol;
  _Float16* aDst0 = &Ah[w * 512];
  _Float16* aDst1 = &Ah[(w + 4) * 512];
  _Float16* bDst0 = &Bh[w * 512];
  _Float16* bDst1 = &Bh[(w + 4) * 512];

  int fr = lane & 15;
  int kb = (lane >> 4) * 8;
  const _Float16* aBase = &Ah[(wr * 64 + fr) * 32 + kb];
  const _Float16* bBase = &Bh[(wc * 64 + fr) * 32 + kb];

  f32x4 acc[4][4] = {};

  for (int k0 = 0; k0 < K; k0 += 32) {
    GLOAD16(aSrc0, aDst0);
    GLOAD16(aSrc1, aDst1);
    GLOAD16(bSrc0, bDst0);
    GLOAD16(bSrc1, bDst1);
    __syncthreads();

    f16x8 av[4], bv[4];
#pragma unroll
    for (int m = 0; m < 4; m++) av[m] = *(const f16x8*)(aBase + m * 512);
#pragma unroll
    for (int n = 0; n < 4; n++) bv[n] = *(const f16x8*)(bBase + n * 512);
#pragma unroll
    for (int m = 0; m < 4; m++)
#pragma unroll
      for (int n = 0; n < 4; n++)
        acc[m][n] = __builtin_amdgcn_mfma_f32_16x16x32_f16(av[m], bv[n], acc[m][n], 0, 0, 0);
    __syncthreads();

    aSrc0 += 32; aSrc1 += 32; bSrc0 += 32; bSrc1 += 32;
  }

  float* Cw = nullptr; int ldc = 2048, cb0 = 0;
  if (MODE == 0) {
    int nt = blockIdx.x;
    if (nt < 16)      { Cw = g.Cq; ldc = 2048; cb0 = 0; }
    else if (nt < 20) { Cw = g.Ck; ldc = 512;  cb0 = 2048; }
    else              { Cw = g.Cv; ldc = 512;  cb0 = 2560; }
  }
  int rbase = (lane >> 4) * 4;
#pragma unroll
  for (int m = 0; m < 4; m++) {
#pragma unroll
    for (int r = 0; r < 4; r++) {
      int gr = m0 + wr * 64 + m * 16 + rbase + r;
      int tok = 0; float sc = 0.f;
      if (MODE == 3) {
        tok = g.perm[gr];
        sc = g.rwbuf[gr];
      }
#pragma unroll
      for (int n = 0; n < 4; n++) {
        int gc = n0 + wc * 64 + n * 16 + fr;
        float v = acc[m][n][r];
        if (MODE == 0) {
          Cw[(size_t)gr * ldc + (gc - cb0)] = v;
        } else if (MODE == 1) {
          g.C[(size_t)gr * 2048 + gc] = v + g.resid[(size_t)gr * 2048 + gc];
        } else if (MODE == 2) {
          g.Ch[(size_t)gr * 2048 + gc] = (_Float16)v;
        } else {
          if (tok >= 0) g.C[(size_t)gr * 2048 + gc] = v * sc;
        }
      }
    }
  }
}

// ---------------------------------------------------------------- MFMA flash attention
// Qh [S][2048] f16 (post norm+rope), Kh [S][512] f16, Vt [512][S] f16 (pre-transposed).
// Block: 4 waves, 64 q-rows (16/wave); KV tiles of 32. fp32 online softmax.
__global__ __launch_bounds__(256) void k_attn_mfma(
    const _Float16* __restrict__ Qh, const _Float16* __restrict__ Kh,
    const _Float16* __restrict__ Vt, _Float16* __restrict__ AO) {
  __shared__ _Float16 Ks[32][136];   // [kv][d]   pad: 272B rows, 16B aligned
  __shared__ _Float16 Vs[128][40];   // [d][kv]   pad: 80B rows
  __shared__ _Float16 Ps[4][16][40]; // per-wave P tile [q][kv]
  int h = blockIdx.y;
  int hk = h >> 2;
  int q0 = blockIdx.x * 64;
  int tid = threadIdx.x, lane = tid & 63, w = tid >> 6;
  int fr = lane & 15, kq = lane >> 4;

  // Q a-frags: wave's 16 rows; A row = lane&15, k = kq*8 + ks*32
  f16x8 qf[4];
  {
    const _Float16* qp = Qh + (size_t)(q0 + w * 16 + fr) * 2048 + h * HD + kq * 8;
#pragma unroll
    for (int s = 0; s < 4; s++) qf[s] = *(const f16x8*)(qp + s * 32);
  }

  f32x4 acc[8] = {};     // O accum: 8 d-blocks of 16x16 C-frags
  float mrow[4], lrow[4];
#pragma unroll
  for (int i = 0; i < 4; i++) { mrow[i] = -1e30f; lrow[i] = 0.f; }

  int ktend = q0 + 64;
  for (int kt = 0; kt < ktend; kt += 32) {
    __syncthreads();  // protect Ks/Vs from previous iteration's reads
    // stage K tile (32 kv x 128 d)
#pragma unroll
    for (int it = 0; it < 2; it++) {
      int row = (tid >> 4) + it * 16;
      int seg = tid & 15;
      *(f16x8*)&Ks[row][seg * 8] =
          *(const f16x8*)(Kh + (size_t)(kt + row) * 512 + hk * HD + seg * 8);
    }
    // stage V^T tile (128 d x 32 kv)
    {
      int d = tid >> 1, hh = tid & 1;
      const _Float16* vsrc = Vt + ((size_t)hk * HD + d) * 2048 + kt + hh * 16;
      *(f16x8*)&Vs[d][hh * 16] = *(const f16x8*)(vsrc);
      *(f16x8*)&Vs[d][hh * 16 + 8] = *(const f16x8*)(vsrc + 8);
    }
    __syncthreads();

    // S = Q @ K^T  (16q x 32kv as two 16x16 frags)
    f32x4 s0 = {}, s1 = {};
#pragma unroll
    for (int ks = 0; ks < 4; ks++) {
      f16x8 kf0 = *(const f16x8*)&Ks[fr][ks * 32 + kq * 8];
      f16x8 kf1 = *(const f16x8*)&Ks[16 + fr][ks * 32 + kq * 8];
      s0 = __builtin_amdgcn_mfma_f32_16x16x32_f16(qf[ks], kf0, s0, 0, 0, 0);
      s1 = __builtin_amdgcn_mfma_f32_16x16x32_f16(qf[ks], kf1, s1, 0, 0, 0);
    }

    // online softmax; C-frag: row = kq*4+reg, col = fr (+16)
    float corrv[4];
    int gqb = q0 + w * 16 + kq * 4;
#pragma unroll
    for (int reg = 0; reg < 4; reg++) {
      int gq = gqb + reg;
      float a = s0[reg] * ATT_SCALE + ((kt + fr) > gq ? -1e9f : 0.f);
      float b = s1[reg] * ATT_SCALE + ((kt + fr + 16) > gq ? -1e9f : 0.f);
      float t = fmaxf(a, b);
      t = fmaxf(t, __shfl_xor(t, 1));
      t = fmaxf(t, __shfl_xor(t, 2));
      t = fmaxf(t, __shfl_xor(t, 4));
      t = fmaxf(t, __shfl_xor(t, 8));
      float mnew = fmaxf(mrow[reg], t);
      float corr = __expf(mrow[reg] - mnew);
      a = __expf(a - mnew);
      b = __expf(b - mnew);
      float rs = a + b;
      rs += __shfl_xor(rs, 1);
      rs += __shfl_xor(rs, 2);
      rs += __shfl_xor(rs, 4);
      rs += __shfl_xor(rs, 8);
      lrow[reg] = lrow[reg] * corr + rs;
      mrow[reg] = mnew;
      corrv[reg] = corr;
      Ps[w][kq * 4 + reg][fr] = (_Float16)a;
      Ps[w][kq * 4 + reg][16 + fr] = (_Float16)b;
    }
    // rescale O
#pragma unroll
    for (int nb = 0; nb < 8; nb++)
#pragma unroll
      for (int reg = 0; reg < 4; reg++) acc[nb][reg] *= corrv[reg];

    // PV: A = P (row = fr, k = kq*8+j), B = V via Vs[d][kv]
    f16x8 pf = *(const f16x8*)&Ps[w][fr][kq * 8];
#pragma unroll
    for (int nb = 0; nb < 8; nb++) {
      f16x8 vf = *(const f16x8*)&Vs[nb * 16 + fr][kq * 8];
      acc[nb] = __builtin_amdgcn_mfma_f32_16x16x32_f16(pf, vf, acc[nb], 0, 0, 0);
    }
  }

  float inv[4];
#pragma unroll
  for (int reg = 0; reg < 4; reg++) inv[reg] = 1.0f / lrow[reg];
#pragma unroll
  for (int nb = 0; nb < 8; nb++)
#pragma unroll
    for (int reg = 0; reg < 4; reg++) {
      int q = q0 + w * 16 + kq * 4 + reg;
      AO[(size_t)q * 2048 + h * HD + nb * 16 + fr] = (_Float16)(acc[nb][reg] * inv[reg]);
    }
}

// ---------------------------------------------------------------- MoE routing (fp32)
__global__ __launch_bounds__(256) void k_gate(
    const float* __restrict__ xn, const float* __restrict__ gw, float* __restrict__ logits) {
  int t = blockIdx.x;
  float a[8] = {0, 0, 0, 0, 0, 0, 0, 0};
#pragma unroll
  for (int i = 0; i < 8; i++) {
    int hh = threadIdx.x + i * 256;
    float xv = xn[(size_t)t * HDIM + hh];
    const float* gp = gw + (size_t)hh * 8;
    float4 g0 = *(const float4*)gp;
    float4 g1 = *(const float4*)(gp + 4);
    a[0] = fmaf(xv, g0.x, a[0]); a[1] = fmaf(xv, g0.y, a[1]);
    a[2] = fmaf(xv, g0.z, a[2]); a[3] = fmaf(xv, g0.w, a[3]);
    a[4] = fmaf(xv, g1.x, a[4]); a[5] = fmaf(xv, g1.y, a[5]);
    a[6] = fmaf(xv, g1.z, a[6]); a[7] = fmaf(xv, g1.w, a[7]);
  }
#pragma unroll
  for (int e = 0; e < 8; e++)
#pragma unroll
    for (int off = 32; off > 0; off >>= 1) a[e] += __shfl_down(a[e], off, 64);
  __shared__ float red[4][8];
  int lane = threadIdx.x & 63, wid = threadIdx.x >> 6;
  if (lane == 0) {
#pragma unroll
    for (int e = 0; e < 8; e++) red[wid][e] = a[e];
  }
  __syncthreads();
  if (threadIdx.x < 8) {
    int e = threadIdx.x;
    logits[(size_t)t * 8 + e] = red[0][e] + red[1][e] + red[2][e] + red[3][e];
  }
}

__global__ __launch_bounds__(256) void k_route(
    const float* __restrict__ logits, const float* __restrict__ bias,
    int* __restrict__ counts, int* __restrict__ toke, float* __restrict__ tokrw) {
  int t = blockIdx.x * 256 + threadIdx.x;
  if (t >= SDIM) return;
  float s[8], bsc[8];
#pragma unroll
  for (int e = 0; e < 8; e++) {
    float lg = logits[(size_t)t * 8 + e];
    s[e] = 1.0f / (1.0f + expf(-lg));
    bsc[e] = s[e] + bias[e];
  }
  int i0 = 0;
#pragma unroll
  for (int e = 1; e < 8; e++) if (bsc[e] > bsc[i0]) i0 = e;
  int i1 = (i0 == 0) ? 1 : 0;
#pragma unroll
  for (int e = 0; e < 8; e++) if (e != i0 && bsc[e] > bsc[i1]) i1 = e;
  float r0 = s[i0], r1 = s[i1];
  float den = fmaxf(r0 + r1, 1e-12f);
  atomicAdd(&counts[i0], 1);
  atomicAdd(&counts[i1], 1);
  toke[t * 2] = i0; toke[t * 2 + 1] = i1;
  tokrw[t * 2] = r0 / den; tokrw[t * 2 + 1] = r1 / den;
}

__global__ void k_offsets(const int* __restrict__ counts, int* __restrict__ aoff) {
  if (threadIdx.x == 0 && blockIdx.x == 0) {
    int o = 0;
#pragma unroll
    for (int e = 0; e < 8; e++) { aoff[e] = o; o += (counts[e] + 127) & ~127; }
    aoff[8] = o;
  }
}

__global__ __launch_bounds__(256) void k_scatter(
    const int* __restrict__ toke, const float* __restrict__ tokrw,
    const int* __restrict__ aoff, int* __restrict__ cursor,
    int* __restrict__ perm, float* __restrict__ rwbuf, int* __restrict__ tokslot) {
  int t = blockIdx.x * 256 + threadIdx.x;
  if (t >= SDIM) return;
#pragma unroll
  for (int sl = 0; sl < 2; sl++) {
    int e = toke[t * 2 + sl];
    int pos = atomicAdd(&cursor[e], 1);
    int j = aoff[e] + pos;
    perm[j] = t;
    rwbuf[j] = tokrw[t * 2 + sl];
    tokslot[t * 2 + sl] = j;
  }
}

// ---------------------------------------------------------------- silu(g)*u -> Hb (f16)
__global__ __launch_bounds__(128) void k_silu(
    const _Float16* __restrict__ G, const int* __restrict__ perm,
    _Float16* __restrict__ Hb) {
  int j = blockIdx.x;
  int c = threadIdx.x;
  f16x8 o;
  if (perm[j] < 0) {
#pragma unroll
    for (int t = 0; t < 8; t++) o[t] = (_Float16)0.f;
  } else {
    f16x8 g8 = *(const f16x8*)(G + (size_t)j * 2048 + c * 8);
    f16x8 u8 = *(const f16x8*)(G + (size_t)j * 2048 + 1024 + c * 8);
#pragma unroll
    for (int t = 0; t < 8; t++) {
      float gv = (float)g8[t], uv = (float)u8[t];
      o[t] = (_Float16)(gv / (1.0f + expf(-gv)) * uv);
    }
  }
  *(f16x8*)(Hb + (size_t)j * 1024 + c * 8) = o;
}

__global__ __launch_bounds__(256) void k_fadd(
    float* __restrict__ out, const float* __restrict__ Yb, const int* __restrict__ tokslot) {
  int t = blockIdx.x;
  int j0 = tokslot[t * 2], j1 = tokslot[t * 2 + 1];
  const float* y0 = Yb + (size_t)j0 * HDIM;
  const float* y1 = Yb + (size_t)j1 * HDIM;
  float* orow = out + (size_t)t * HDIM;
  for (int c = threadIdx.x * 4; c < HDIM; c += 1024) {
    float4 o = *(float4*)(orow + c);
    float4 p = *(const float4*)(y0 + c);
    float4 q = *(const float4*)(y1 + c);
    o.x += p.x + q.x; o.y += p.y + q.y; o.z += p.z + q.z; o.w += p.w + q.w;
    *(float4*)(orow + c) = o;
  }
}

// ---------------------------------------------------------------- launch
extern "C" void kernel_launch(void* const* d_in, const int* in_sizes, int n_in,
                              void* d_out, int out_size, void* d_ws, size_t ws_size,
                              hipStream_t stream) {
  const float* hidden = (const float*)d_in[0];
  const float* cosb   = (const float*)d_in[2];
  const float* sinb   = (const float*)d_in[3];
  const float* ln1w   = (const float*)d_in[4];
  const float* ln2w   = (const float*)d_in[5];
  const float* wq     = (const float*)d_in[6];
  const float* wk     = (const float*)d_in[7];
  const float* wv     = (const float*)d_in[8];
  const float* wo     = (const float*)d_in[9];
  const float* qnw    = (const float*)d_in[10];
  const float* knw    = (const float*)d_in[11];
  const float* gatew  = (const float*)d_in[12];
  const float* biase  = (const float*)d_in[13];
  const float* w1     = (const float*)d_in[14];
  const float* w3     = (const float*)d_in[15];
  const float* w2     = (const float*)d_in[16];
  float* out = (float*)d_out;

  char* base = (char*)d_ws;
  size_t off = 0;
  auto alloc = [&](size_t bytes) {
    void* p = base + off;
    off = (off + bytes + 255) & ~(size_t)255;
    return p;
  };
  _Float16* xnh  = (_Float16*)alloc((size_t)SDIM * HDIM * 2);
  float* Qb      = (float*)alloc((size_t)SDIM * HDIM * 4);
  float* Kb      = (float*)alloc((size_t)SDIM * 512 * 4);
  float* Vb      = (float*)alloc((size_t)SDIM * 512 * 4);
  _Float16* Qhh  = (_Float16*)alloc((size_t)SDIM * HDIM * 2);
  _Float16* Khh  = (_Float16*)alloc((size_t)SDIM * 512 * 2);
  _Float16* Vth  = (_Float16*)alloc((size_t)512 * SDIM * 2);
  _Float16* AOh  = (_Float16*)alloc((size_t)SDIM * HDIM * 2);
  float* xn2     = (float*)alloc((size_t)SDIM * HDIM * 4);
  _Float16* xn2h = (_Float16*)alloc((size_t)SDIM * HDIM * 2);
  _Float16* Gbuf = (_Float16*)alloc((size_t)CAP * 2048 * 2);
  _Float16* Hbh  = (_Float16*)alloc((size_t)CAP * IDIM * 2);
  float* Yb      = (float*)alloc((size_t)CAP * HDIM * 4);
  _Float16* qkvt = (_Float16*)alloc((size_t)3072 * 2048 * 2);
  _Float16* wot  = (_Float16*)alloc((size_t)2048 * 2048 * 2);
  _Float16* w13t = (_Float16*)alloc((size_t)8 * 2048 * 2048 * 2);
  _Float16* w2t  = (_Float16*)alloc((size_t)8 * 2048 * 1024 * 2);
  float* logits  = (float*)alloc((size_t)SDIM * 8 * 4);
  float* rwbuf   = (float*)alloc((size_t)CAP * 4);
  float* tokrw   = (float*)alloc((size_t)SDIM * 2 * 4);
  int* counts    = (int*)alloc(16 * 4);
  int* aoff      = (int*)alloc(12 * 4);
  int* perm      = (int*)alloc((size_t)CAP * 4);
  int* toke      = (int*)alloc((size_t)SDIM * 2 * 4);
  int* tokslot   = (int*)alloc((size_t)SDIM * 2 * 4);
  int* cursor    = counts + 8;

  hipMemsetAsync(counts, 0, 16 * sizeof(int), stream);
  hipMemsetAsync(perm, 0xFF, CAP * sizeof(int), stream);

  // weight transpose+convert to f16 [N][K]
  k_convT<<<dim3(32, 32, 1), 256, 0, stream>>>(wq, qkvt, 2048, 2048, 0, 0);
  k_convT<<<dim3(8, 32, 1), 256, 0, stream>>>(wk, qkvt + (size_t)2048 * 2048, 2048, 512, 0, 0);
  k_convT<<<dim3(8, 32, 1), 256, 0, stream>>>(wv, qkvt + (size_t)2560 * 2048, 2048, 512, 0, 0);
  k_convT<<<dim3(32, 32, 1), 256, 0, stream>>>(wo, wot, 2048, 2048, 0, 0);
  k_convT<<<dim3(16, 32, 8), 256, 0, stream>>>(w1, w13t, 2048, 1024,
                                               (long)2048 * 1024, (long)2048 * 2048);
  k_convT<<<dim3(16, 32, 8), 256, 0, stream>>>(w3, w13t + (size_t)1024 * 2048, 2048, 1024,
                                               (long)2048 * 1024, (long)2048 * 2048);
  k_convT<<<dim3(32, 16, 8), 256, 0, stream>>>(w2, w2t, 1024, 2048,
                                               (long)1024 * 2048, (long)2048 * 1024);

  // 1. ln1 -> xnh (f16)
  k_rmsnorm<<<SDIM, 256, 0, stream>>>(hidden, ln1w, nullptr, xnh);

  // 2. QKV MFMA (fp32 out)
  MArgs a0 = {};
  a0.A = xnh; a0.Bt = qkvt; a0.Kdim = HDIM;
  a0.Cq = Qb; a0.Ck = Kb; a0.Cv = Vb;
  k_mfma<0><<<dim3(24, 16), 256, 0, stream>>>(a0);

  // 3. q/k rmsnorm + rope -> f16; V transpose -> f16 [512][2048]
  k_qknorm_rope<<<SDIM, 256, 0, stream>>>(Qb, qnw, cosb, sinb, NHQ * HD, Qhh);
  k_qknorm_rope<<<SDIM, 256, 0, stream>>>(Kb, knw, cosb, sinb, NKVH * HD, Khh);
  k_convT<<<dim3(8, 32, 1), 256, 0, stream>>>(Vb, Vth, 2048, 512, 0, 0);

  // 4. MFMA flash attention -> AOh (f16)
  k_attn_mfma<<<dim3(SDIM / 64, NHQ), 256, 0, stream>>>(Qhh, Khh, Vth, AOh);

  // 5. wo + residual -> out
  MArgs a1 = {};
  a1.A = AOh; a1.Bt = wot; a1.Kdim = HDIM; a1.C = out; a1.resid = hidden;
  k_mfma<1><<<dim3(16, 16), 256, 0, stream>>>(a1);

  // 6. ln2 -> xn2 (fp32 for gate) + xn2h (f16 for MoE)
  k_rmsnorm<<<SDIM, 256, 0, stream>>>(out, ln2w, xn2, xn2h);

  // 7. routing
  k_gate<<<SDIM, 256, 0, stream>>>(xn2, gatew, logits);
  k_route<<<8, 256, 0, stream>>>(logits, biase, counts, toke, tokrw);
  k_offsets<<<1, 64, 0, stream>>>(counts, aoff);
  k_scatter<<<8, 256, 0, stream>>>(toke, tokrw, aoff, cursor, perm, rwbuf, tokslot);

  // 8. MoE up: G = gather(xn2h) @ [w1|w3]^T (f16 out)
  MArgs a2 = {};
  a2.A = xn2h; a2.Bt = w13t; a2.Kdim = HDIM; a2.Ch = Gbuf;
  a2.perm = perm; a2.aoff = aoff;
  k_mfma<2><<<dim3(16, CAP / 128), 256, 0, stream>>>(a2);

  k_silu<<<CAP, 128, 0, stream>>>(Gbuf, perm, Hbh);

  // 9. MoE down: Yb = (Hb @ w2^T) * rw
  MArgs a3 = {};
  a3.A = Hbh; a3.Bt = w2t; a3.Kdim = IDIM; a3.C = Yb;
  a3.perm = perm; a3.aoff = aoff; a3.rwbuf = rwbuf;
  k_mfma<3><<<dim3(16, CAP / 128), 256, 0, stream>>>(a3);

  // 10. final residual add
  k_fadd<<<SDIM, 256, 0, stream>>>(out, Yb, tokslot);
}

// Round 10
// 720.782 us; speedup vs baseline: 3.9989x; 1.0432x over previous
//
#include <hip/hip_runtime.h>
#include <hip/hip_bf16.h>
#include <cstdint>

// MiniMax M2 decoder layer — round 9 resubmit: GEMM retile 128x64 (occupancy) + attn KVBLK=64.
// fp32 kept for: rmsnorms, q/k-norm+RoPE, softmax stats, gate/routing, residuals.

#define SDIM 2048
#define HDIM 2048
#define NHQ 16
#define NKVH 4
#define HD 128
#define RDIM 64
#define IDIM 1024
#define CAP 5120
#define ATT_SCALE 0.08838834764831845f
#define EPS 1e-6f

typedef _Float16 f16x8 __attribute__((ext_vector_type(8)));
typedef _Float16 f16x4 __attribute__((ext_vector_type(4)));
typedef float f32x4 __attribute__((ext_vector_type(4)));

#define GLOAD16(g, l)                                                       \
  __builtin_amdgcn_global_load_lds(                                         \
      (const __attribute__((address_space(1))) void*)(g),                   \
      (__attribute__((address_space(3))) void*)(l), 16, 0, 0)

// ---------------------------------------------------------------- reductions
__device__ __forceinline__ float block_reduce_sum_256(float v) {
  __shared__ float sb[4];
#pragma unroll
  for (int off = 32; off > 0; off >>= 1) v += __shfl_down(v, off, 64);
  int lane = threadIdx.x & 63, wid = threadIdx.x >> 6;
  if (lane == 0) sb[wid] = v;
  __syncthreads();
  return sb[0] + sb[1] + sb[2] + sb[3];
}

// ---------------------------------------------------------------- rmsnorm H=2048
__global__ __launch_bounds__(256) void k_rmsnorm(
    const float* __restrict__ x, const float* __restrict__ w,
    float* __restrict__ outf, _Float16* __restrict__ outh) {
  int row = blockIdx.x;
  const float* xr = x + (size_t)row * HDIM;
  int i0 = threadIdx.x * 4, i1 = i0 + 1024;
  float4 a = *(const float4*)(xr + i0);
  float4 b = *(const float4*)(xr + i1);
  float ss = a.x*a.x + a.y*a.y + a.z*a.z + a.w*a.w +
             b.x*b.x + b.y*b.y + b.z*b.z + b.w*b.w;
  float tot = block_reduce_sum_256(ss);
  float r = rsqrtf(tot * (1.0f / HDIM) + EPS);
  float4 wa = *(const float4*)(w + i0);
  float4 wb = *(const float4*)(w + i1);
  float4 oa, ob;
  oa.x = wa.x * (a.x * r); oa.y = wa.y * (a.y * r);
  oa.z = wa.z * (a.z * r); oa.w = wa.w * (a.w * r);
  ob.x = wb.x * (b.x * r); ob.y = wb.y * (b.y * r);
  ob.z = wb.z * (b.z * r); ob.w = wb.w * (b.w * r);
  if (outf) {
    *(float4*)(outf + (size_t)row * HDIM + i0) = oa;
    *(float4*)(outf + (size_t)row * HDIM + i1) = ob;
  }
  f16x4 ha, hb;
  ha[0] = (_Float16)oa.x; ha[1] = (_Float16)oa.y;
  ha[2] = (_Float16)oa.z; ha[3] = (_Float16)oa.w;
  hb[0] = (_Float16)ob.x; hb[1] = (_Float16)ob.y;
  hb[2] = (_Float16)ob.z; hb[3] = (_Float16)ob.w;
  *(f16x4*)(outh + (size_t)row * HDIM + i0) = ha;
  *(f16x4*)(outh + (size_t)row * HDIM + i1) = hb;
}

// ---------------------------------------------------------------- transpose+convert fp32 [R][C] -> f16 [C][R]
__global__ __launch_bounds__(256) void k_convT(
    const float* __restrict__ src, _Float16* __restrict__ dst,
    int R, int C, long srcZ, long dstZ) {
  __shared__ float T[64][65];
  src += (size_t)blockIdx.z * srcZ;
  dst += (size_t)blockIdx.z * dstZ;
  int r0 = blockIdx.y * 64, c0 = blockIdx.x * 64;
  int tr = threadIdx.x >> 2, tq = threadIdx.x & 3;
  const float* sp = src + (size_t)(r0 + tr) * C + c0 + tq * 16;
#pragma unroll
  for (int i = 0; i < 4; i++)
    *(float4*)&T[tr][tq * 16 + i * 4] = *(const float4*)(sp + i * 4);
  __syncthreads();
  int oc = threadIdx.x >> 2;  // output row = source col
  int h = threadIdx.x & 3;    // 16-wide k chunk
  _Float16* dp = dst + (size_t)(c0 + oc) * R + r0 + h * 16;
  f16x8 u0, u1;
#pragma unroll
  for (int j = 0; j < 8; j++) u0[j] = (_Float16)T[h * 16 + j][oc];
#pragma unroll
  for (int j = 0; j < 8; j++) u1[j] = (_Float16)T[h * 16 + 8 + j][oc];
  *(f16x8*)dp = u0;
  *((f16x8*)dp + 1) = u1;
}

// ---------------------------------------------------------------- q/k norm + rope (fp32 in, f16 out)
__global__ __launch_bounds__(256) void k_qknorm_rope(
    const float* __restrict__ X, const float* __restrict__ w,
    const float* __restrict__ cosb, const float* __restrict__ sinb, int len,
    _Float16* __restrict__ outh) {
  int row = blockIdx.x;
  const float* xr = X + (size_t)row * len;
  __shared__ float xs[HDIM];
  float ss = 0.f;
  for (int i = threadIdx.x * 4; i < len; i += 1024) {
    float4 v = *(const float4*)(xr + i);
    *(float4*)(xs + i) = v;
    ss += v.x*v.x + v.y*v.y + v.z*v.z + v.w*v.w;
  }
  float tot = block_reduce_sum_256(ss);
  float r = rsqrtf(tot / (float)len + EPS);
  const float* cr = cosb + (size_t)row * RDIM;
  const float* sr = sinb + (size_t)row * RDIM;
  _Float16* orow = outh + (size_t)row * len;
  for (int i = threadIdx.x; i < len; i += 256) {
    int d = i & (HD - 1);
    float xv = xs[i] * r * w[i];
    float o;
    if (d < RDIM) {
      float c = cr[d], s = sr[d];
      if (d < RDIM / 2) {
        float pn = xs[i + RDIM / 2] * r * w[i + RDIM / 2];
        o = xv * c - pn * s;
      } else {
        float pn = xs[i - RDIM / 2] * r * w[i - RDIM / 2];
        o = xv * c + pn * s;
      }
    } else {
      o = xv;
    }
    orow[i] = (_Float16)o;
  }
}

// ---------------------------------------------------------------- MFMA GEMM (tile 128x64, 4 waves of 64x32)
// A: f16 [M][K] (MODE2: rows gathered via perm). Bt: f16 [N][K].
// MODE 0: QKV packed outputs (fp32). MODE 1: out = A@B + resid (fp32).
// MODE 2: G = A@B (f16, grouped experts). MODE 3: Yb = (A@B)*rw (fp32, grouped).
struct MArgs {
  const _Float16* A;
  const _Float16* Bt;
  int Kdim;
  float* Cq; float* Ck; float* Cv;   // mode 0
  float* C;                          // mode 1 / 3
  const float* resid;                // mode 1
  _Float16* Ch;                      // mode 2
  const int* perm; const int* aoff; const float* rwbuf;
};

template <int MODE>
__global__ __launch_bounds__(256) void k_mfma(MArgs g) {
  __shared__ _Float16 Ah[128 * 32];
  __shared__ _Float16 Bh[64 * 32];
  int tid = threadIdx.x;
  int lane = tid & 63, w = tid >> 6;
  int wr = w >> 1, wc = w & 1;
  int m0 = blockIdx.y * 128;
  int n0 = blockIdx.x * 64;   // MODE0: global col in packed [Q|K|V] 3072 space
  int K = g.Kdim;

  const _Float16* Bt = g.Bt;
  if (MODE >= 2) {
    if (m0 >= g.aoff[8]) return;
    int expert = 0;
    while (g.aoff[expert + 1] <= m0) expert++;
    Bt += (size_t)expert * (size_t)((MODE == 2) ? 2048 * 2048 : 2048 * 1024);
  }

  // staging: A has 8 chunks of 16 rows (wave w owns chunks w, w+4); B has 4 (wave w owns chunk w)
  int crow = lane >> 2;
  int ccol = (lane & 3) * 8;
  int r0 = m0 + w * 16 + crow, r1 = m0 + (w + 4) * 16 + crow;
  if (MODE == 2) {
    int p0 = g.perm[r0], p1 = g.perm[r1];
    r0 = (p0 < 0) ? 0 : p0;
    r1 = (p1 < 0) ? 0 : p1;
  }
  const _Float16* aSrc0 = g.A + (size_t)r0 * K + ccol;
  const _Float16* aSrc1 = g.A + (size_t)r1 * K + ccol;
  const _Float16* bSrc  = Bt + (size_t)(n0 + w * 16 + crow) * K + ccol;
  _Float16* aDst0 = &Ah[w * 512];
  _Float16* aDst1 = &Ah[(w + 4) * 512];
  _Float16* bDst  = &Bh[w * 512];

  int fr = lane & 15;
  int kb = (lane >> 4) * 8;
  const _Float16* aBase = &Ah[(wr * 64 + fr) * 32 + kb];
  const _Float16* bBase = &Bh[(wc * 32 + fr) * 32 + kb];

  f32x4 acc[4][2] = {};

  for (int k0 = 0; k0 < K; k0 += 32) {
    GLOAD16(aSrc0, aDst0);
    GLOAD16(aSrc1, aDst1);
    GLOAD16(bSrc, bDst);
    __syncthreads();

    f16x8 av[4], bv[2];
#pragma unroll
    for (int m = 0; m < 4; m++) av[m] = *(const f16x8*)(aBase + m * 512);
#pragma unroll
    for (int n = 0; n < 2; n++) bv[n] = *(const f16x8*)(bBase + n * 512);
#pragma unroll
    for (int m = 0; m < 4; m++)
#pragma unroll
      for (int n = 0; n < 2; n++)
        acc[m][n] = __builtin_amdgcn_mfma_f32_16x16x32_f16(av[m], bv[n], acc[m][n], 0, 0, 0);
    __syncthreads();

    aSrc0 += 32; aSrc1 += 32; bSrc += 32;
  }

  float* Cw = nullptr; int ldc = 2048, cb0 = 0;
  if (MODE == 0) {
    if (n0 < 2048)      { Cw = g.Cq; ldc = 2048; cb0 = 0; }
    else if (n0 < 2560) { Cw = g.Ck; ldc = 512;  cb0 = 2048; }
    else                { Cw = g.Cv; ldc = 512;  cb0 = 2560; }
  }
  int rbase = (lane >> 4) * 4;
#pragma unroll
  for (int m = 0; m < 4; m++) {
#pragma unroll
    for (int r = 0; r < 4; r++) {
      int gr = m0 + wr * 64 + m * 16 + rbase + r;
      int tok = 0; float sc = 0.f;
      if (MODE == 3) {
        tok = g.perm[gr];
        sc = g.rwbuf[gr];
      }
#pragma unroll
      for (int n = 0; n < 2; n++) {
        int gc = n0 + wc * 32 + n * 16 + fr;
        float v = acc[m][n][r];
        if (MODE == 0) {
          Cw[(size_t)gr * ldc + (gc - cb0)] = v;
        } else if (MODE == 1) {
          g.C[(size_t)gr * 2048 + gc] = v + g.resid[(size_t)gr * 2048 + gc];
        } else if (MODE == 2) {
          g.Ch[(size_t)gr * 2048 + gc] = (_Float16)v;
        } else {
          if (tok >= 0) g.C[(size_t)gr * 2048 + gc] = v * sc;
        }
      }
    }
  }
}

// ---------------------------------------------------------------- MFMA flash attention (KVBLK=64)
// Qh [S][2048] f16 (post norm+rope), Kh [S][512] f16, Vt [512][S] f16 (pre-transposed).
// Block: 4 waves, 64 q-rows (16/wave); KV tiles of 64. fp32 online softmax.
__global__ __launch_bounds__(256) void k_attn_mfma(
    const _Float16* __restrict__ Qh, const _Float16* __restrict__ Kh,
    const _Float16* __restrict__ Vt, _Float16* __restrict__ AO) {
  __shared__ _Float16 Ks[64][136];   // [kv][d]  17 KB; row stride 68 dw -> 2-way max
  __shared__ _Float16 Vs[128][72];   // [d][kv]  18.4 KB; row stride 36 dw -> 2-way max
  __shared__ _Float16 Ps[4][16][72]; // per-wave P tile [q][kv 0..63]  9.2 KB
  int h = blockIdx.y;
  int hk = h >> 2;
  int q0 = blockIdx.x * 64;
  int tid = threadIdx.x, lane = tid & 63, w = tid >> 6;
  int fr = lane & 15, kq = lane >> 4;

  // Q a-frags: wave's 16 rows; A row = lane&15, k = kq*8 + ks*32
  f16x8 qf[4];
  {
    const _Float16* qp = Qh + (size_t)(q0 + w * 16 + fr) * 2048 + h * HD + kq * 8;
#pragma unroll
    for (int s = 0; s < 4; s++) qf[s] = *(const f16x8*)(qp + s * 32);
  }

  f32x4 acc[8] = {};     // O accum: 8 d-blocks of 16x16 C-frags
  float mrow[4], lrow[4];
#pragma unroll
  for (int i = 0; i < 4; i++) { mrow[i] = -1e30f; lrow[i] = 0.f; }

  int ktend = q0 + 64;
  for (int kt = 0; kt < ktend; kt += 64) {
    __syncthreads();  // protect Ks/Vs from previous iteration's reads
    // stage K tile (64 kv x 128 d): thread -> row tid>>2, 32 halves at (tid&3)*32
    {
      int row = tid >> 2;
      int seg = (tid & 3) * 32;
      const _Float16* ksrc = Kh + (size_t)(kt + row) * 512 + hk * HD + seg;
#pragma unroll
      for (int j = 0; j < 4; j++)
        *(f16x8*)&Ks[row][seg + j * 8] = *(const f16x8*)(ksrc + j * 8);
    }
    // stage V^T tile (128 d x 64 kv): thread -> row tid>>1, 32 halves at (tid&1)*32
    {
      int d = tid >> 1;
      int seg = (tid & 1) * 32;
      const _Float16* vsrc = Vt + ((size_t)hk * HD + d) * 2048 + kt + seg;
#pragma unroll
      for (int j = 0; j < 4; j++)
        *(f16x8*)&Vs[d][seg + j * 8] = *(const f16x8*)(vsrc + j * 8);
    }
    __syncthreads();

    // S = Q @ K^T  (16q x 64kv as four 16x16 frags)
    f32x4 s[4] = {};
#pragma unroll
    for (int ks = 0; ks < 4; ks++) {
#pragma unroll
      for (int j = 0; j < 4; j++) {
        f16x8 kf = *(const f16x8*)&Ks[j * 16 + fr][ks * 32 + kq * 8];
        s[j] = __builtin_amdgcn_mfma_f32_16x16x32_f16(qf[ks], kf, s[j], 0, 0, 0);
      }
    }

    // online softmax over 64 kv; C-frag: row = kq*4+reg, col = fr + 16j
    float corrv[4];
    int gqb = q0 + w * 16 + kq * 4;
#pragma unroll
    for (int reg = 0; reg < 4; reg++) {
      int gq = gqb + reg;
      float e[4];
      float t = -1e30f;
#pragma unroll
      for (int j = 0; j < 4; j++) {
        e[j] = s[j][reg] * ATT_SCALE + ((kt + fr + 16 * j) > gq ? -1e9f : 0.f);
        t = fmaxf(t, e[j]);
      }
      t = fmaxf(t, __shfl_xor(t, 1));
      t = fmaxf(t, __shfl_xor(t, 2));
      t = fmaxf(t, __shfl_xor(t, 4));
      t = fmaxf(t, __shfl_xor(t, 8));
      float mnew = fmaxf(mrow[reg], t);
      float corr = __expf(mrow[reg] - mnew);
      float rs = 0.f;
#pragma unroll
      for (int j = 0; j < 4; j++) {
        e[j] = __expf(e[j] - mnew);
        rs += e[j];
      }
      rs += __shfl_xor(rs, 1);
      rs += __shfl_xor(rs, 2);
      rs += __shfl_xor(rs, 4);
      rs += __shfl_xor(rs, 8);
      lrow[reg] = lrow[reg] * corr + rs;
      mrow[reg] = mnew;
      corrv[reg] = corr;
#pragma unroll
      for (int j = 0; j < 4; j++)
        Ps[w][kq * 4 + reg][16 * j + fr] = (_Float16)e[j];
    }
    // rescale O
#pragma unroll
    for (int nb = 0; nb < 8; nb++)
#pragma unroll
      for (int reg = 0; reg < 4; reg++) acc[nb][reg] *= corrv[reg];

    // PV over k=64: two k-frags (kv 0-31, 32-63)
    f16x8 pf0 = *(const f16x8*)&Ps[w][fr][kq * 8];
    f16x8 pf1 = *(const f16x8*)&Ps[w][fr][32 + kq * 8];
#pragma unroll
    for (int nb = 0; nb < 8; nb++) {
      f16x8 vf0 = *(const f16x8*)&Vs[nb * 16 + fr][kq * 8];
      f16x8 vf1 = *(const f16x8*)&Vs[nb * 16 + fr][32 + kq * 8];
      acc[nb] = __builtin_amdgcn_mfma_f32_16x16x32_f16(pf0, vf0, acc[nb], 0, 0, 0);
      acc[nb] = __builtin_amdgcn_mfma_f32_16x16x32_f16(pf1, vf1, acc[nb], 0, 0, 0);
    }
  }

  float inv[4];
#pragma unroll
  for (int reg = 0; reg < 4; reg++) inv[reg] = 1.0f / lrow[reg];
#pragma unroll
  for (int nb = 0; nb < 8; nb++)
#pragma unroll
    for (int reg = 0; reg < 4; reg++) {
      int q = q0 + w * 16 + kq * 4 + reg;
      AO[(size_t)q * 2048 + h * HD + nb * 16 + fr] = (_Float16)(acc[nb][reg] * inv[reg]);
    }
}

// ---------------------------------------------------------------- MoE routing (fp32)
__global__ __launch_bounds__(256) void k_gate(
    const float* __restrict__ xn, const float* __restrict__ gw, float* __restrict__ logits) {
  int t = blockIdx.x;
  float a[8] = {0, 0, 0, 0, 0, 0, 0, 0};
#pragma unroll
  for (int i = 0; i < 8; i++) {
    int hh = threadIdx.x + i * 256;
    float xv = xn[(size_t)t * HDIM + hh];
    const float* gp = gw + (size_t)hh * 8;
    float4 g0 = *(const float4*)gp;
    float4 g1 = *(const float4*)(gp + 4);
    a[0] = fmaf(xv, g0.x, a[0]); a[1] = fmaf(xv, g0.y, a[1]);
    a[2] = fmaf(xv, g0.z, a[2]); a[3] = fmaf(xv, g0.w, a[3]);
    a[4] = fmaf(xv, g1.x, a[4]); a[5] = fmaf(xv, g1.y, a[5]);
    a[6] = fmaf(xv, g1.z, a[6]); a[7] = fmaf(xv, g1.w, a[7]);
  }
#pragma unroll
  for (int e = 0; e < 8; e++)
#pragma unroll
    for (int off = 32; off > 0; off >>= 1) a[e] += __shfl_down(a[e], off, 64);
  __shared__ float red[4][8];
  int lane = threadIdx.x & 63, wid = threadIdx.x >> 6;
  if (lane == 0) {
#pragma unroll
    for (int e = 0; e < 8; e++) red[wid][e] = a[e];
  }
  __syncthreads();
  if (threadIdx.x < 8) {
    int e = threadIdx.x;
    logits[(size_t)t * 8 + e] = red[0][e] + red[1][e] + red[2][e] + red[3][e];
  }
}

__global__ __launch_bounds__(256) void k_route(
    const float* __restrict__ logits, const float* __restrict__ bias,
    int* __restrict__ counts, int* __restrict__ toke, float* __restrict__ tokrw) {
  int t = blockIdx.x * 256 + threadIdx.x;
  if (t >= SDIM) return;
  float s[8], bsc[8];
#pragma unroll
  for (int e = 0; e < 8; e++) {
    float lg = logits[(size_t)t * 8 + e];
    s[e] = 1.0f / (1.0f + expf(-lg));
    bsc[e] = s[e] + bias[e];
  }
  int i0 = 0;
#pragma unroll
  for (int e = 1; e < 8; e++) if (bsc[e] > bsc[i0]) i0 = e;
  int i1 = (i0 == 0) ? 1 : 0;
#pragma unroll
  for (int e = 0; e < 8; e++) if (e != i0 && bsc[e] > bsc[i1]) i1 = e;
  float r0 = s[i0], r1 = s[i1];
  float den = fmaxf(r0 + r1, 1e-12f);
  atomicAdd(&counts[i0], 1);
  atomicAdd(&counts[i1], 1);
  toke[t * 2] = i0; toke[t * 2 + 1] = i1;
  tokrw[t * 2] = r0 / den; tokrw[t * 2 + 1] = r1 / den;
}

__global__ void k_offsets(const int* __restrict__ counts, int* __restrict__ aoff) {
  if (threadIdx.x == 0 && blockIdx.x == 0) {
    int o = 0;
#pragma unroll
    for (int e = 0; e < 8; e++) { aoff[e] = o; o += (counts[e] + 127) & ~127; }
    aoff[8] = o;
  }
}

__global__ __launch_bounds__(256) void k_scatter(
    const int* __restrict__ toke, const float* __restrict__ tokrw,
    const int* __restrict__ aoff, int* __restrict__ cursor,
    int* __restrict__ perm, float* __restrict__ rwbuf, int* __restrict__ tokslot) {
  int t = blockIdx.x * 256 + threadIdx.x;
  if (t >= SDIM) return;
#pragma unroll
  for (int sl = 0; sl < 2; sl++) {
    int e = toke[t * 2 + sl];
    int pos = atomicAdd(&cursor[e], 1);
    int j = aoff[e] + pos;
    perm[j] = t;
    rwbuf[j] = tokrw[t * 2 + sl];
    tokslot[t * 2 + sl] = j;
  }
}

// ---------------------------------------------------------------- silu(g)*u -> Hb (f16)
__global__ __launch_bounds__(128) void k_silu(
    const _Float16* __restrict__ G, const int* __restrict__ perm,
    _Float16* __restrict__ Hb) {
  int j = blockIdx.x;
  int c = threadIdx.x;
  f16x8 o;
  if (perm[j] < 0) {
#pragma unroll
    for (int t = 0; t < 8; t++) o[t] = (_Float16)0.f;
  } else {
    f16x8 g8 = *(const f16x8*)(G + (size_t)j * 2048 + c * 8);
    f16x8 u8 = *(const f16x8*)(G + (size_t)j * 2048 + 1024 + c * 8);
#pragma unroll
    for (int t = 0; t < 8; t++) {
      float gv = (float)g8[t], uv = (float)u8[t];
      o[t] = (_Float16)(gv / (1.0f + expf(-gv)) * uv);
    }
  }
  *(f16x8*)(Hb + (size_t)j * 1024 + c * 8) = o;
}

__global__ __launch_bounds__(256) void k_fadd(
    float* __restrict__ out, const float* __restrict__ Yb, const int* __restrict__ tokslot) {
  int t = blockIdx.x;
  int j0 = tokslot[t * 2], j1 = tokslot[t * 2 + 1];
  const float* y0 = Yb + (size_t)j0 * HDIM;
  const float* y1 = Yb + (size_t)j1 * HDIM;
  float* orow = out + (size_t)t * HDIM;
  for (int c = threadIdx.x * 4; c < HDIM; c += 1024) {
    float4 o = *(float4*)(orow + c);
    float4 p = *(const float4*)(y0 + c);
    float4 q = *(const float4*)(y1 + c);
    o.x += p.x + q.x; o.y += p.y + q.y; o.z += p.z + q.z; o.w += p.w + q.w;
    *(float4*)(orow + c) = o;
  }
}

// ---------------------------------------------------------------- launch
extern "C" void kernel_launch(void* const* d_in, const int* in_sizes, int n_in,
                              void* d_out, int out_size, void* d_ws, size_t ws_size,
                              hipStream_t stream) {
  const float* hidden = (const float*)d_in[0];
  const float* cosb   = (const float*)d_in[2];
  const float* sinb   = (const float*)d_in[3];
  const float* ln1w   = (const float*)d_in[4];
  const float* ln2w   = (const float*)d_in[5];
  const float* wq     = (const float*)d_in[6];
  const float* wk     = (const float*)d_in[7];
  const float* wv     = (const float*)d_in[8];
  const float* wo     = (const float*)d_in[9];
  const float* qnw    = (const float*)d_in[10];
  const float* knw    = (const float*)d_in[11];
  const float* gatew  = (const float*)d_in[12];
  const float* biase  = (const float*)d_in[13];
  const float* w1     = (const float*)d_in[14];
  const float* w3     = (const float*)d_in[15];
  const float* w2     = (const float*)d_in[16];
  float* out = (float*)d_out;

  char* base = (char*)d_ws;
  size_t off = 0;
  auto alloc = [&](size_t bytes) {
    void* p = base + off;
    off = (off + bytes + 255) & ~(size_t)255;
    return p;
  };
  _Float16* xnh  = (_Float16*)alloc((size_t)SDIM * HDIM * 2);
  float* Qb      = (float*)alloc((size_t)SDIM * HDIM * 4);
  float* Kb      = (float*)alloc((size_t)SDIM * 512 * 4);
  float* Vb      = (float*)alloc((size_t)SDIM * 512 * 4);
  _Float16* Qhh  = (_Float16*)alloc((size_t)SDIM * HDIM * 2);
  _Float16* Khh  = (_Float16*)alloc((size_t)SDIM * 512 * 2);
  _Float16* Vth  = (_Float16*)alloc((size_t)512 * SDIM * 2);
  _Float16* AOh  = (_Float16*)alloc((size_t)SDIM * HDIM * 2);
  float* xn2     = (float*)alloc((size_t)SDIM * HDIM * 4);
  _Float16* xn2h = (_Float16*)alloc((size_t)SDIM * HDIM * 2);
  _Float16* Gbuf = (_Float16*)alloc((size_t)CAP * 2048 * 2);
  _Float16* Hbh  = (_Float16*)alloc((size_t)CAP * IDIM * 2);
  float* Yb      = (float*)alloc((size_t)CAP * HDIM * 4);
  _Float16* qkvt = (_Float16*)alloc((size_t)3072 * 2048 * 2);
  _Float16* wot  = (_Float16*)alloc((size_t)2048 * 2048 * 2);
  _Float16* w13t = (_Float16*)alloc((size_t)8 * 2048 * 2048 * 2);
  _Float16* w2t  = (_Float16*)alloc((size_t)8 * 2048 * 1024 * 2);
  float* logits  = (float*)alloc((size_t)SDIM * 8 * 4);
  float* rwbuf   = (float*)alloc((size_t)CAP * 4);
  float* tokrw   = (float*)alloc((size_t)SDIM * 2 * 4);
  int* counts    = (int*)alloc(16 * 4);
  int* aoff      = (int*)alloc(12 * 4);
  int* perm      = (int*)alloc((size_t)CAP * 4);
  int* toke      = (int*)alloc((size_t)SDIM * 2 * 4);
  int* tokslot   = (int*)alloc((size_t)SDIM * 2 * 4);
  int* cursor    = counts + 8;

  hipMemsetAsync(counts, 0, 16 * sizeof(int), stream);
  hipMemsetAsync(perm, 0xFF, CAP * sizeof(int), stream);

  // weight transpose+convert to f16 [N][K]
  k_convT<<<dim3(32, 32, 1), 256, 0, stream>>>(wq, qkvt, 2048, 2048, 0, 0);
  k_convT<<<dim3(8, 32, 1), 256, 0, stream>>>(wk, qkvt + (size_t)2048 * 2048, 2048, 512, 0, 0);
  k_convT<<<dim3(8, 32, 1), 256, 0, stream>>>(wv, qkvt + (size_t)2560 * 2048, 2048, 512, 0, 0);
  k_convT<<<dim3(32, 32, 1), 256, 0, stream>>>(wo, wot, 2048, 2048, 0, 0);
  k_convT<<<dim3(16, 32, 8), 256, 0, stream>>>(w1, w13t, 2048, 1024,
                                               (long)2048 * 1024, (long)2048 * 2048);
  k_convT<<<dim3(16, 32, 8), 256, 0, stream>>>(w3, w13t + (size_t)1024 * 2048, 2048, 1024,
                                               (long)2048 * 1024, (long)2048 * 2048);
  k_convT<<<dim3(32, 16, 8), 256, 0, stream>>>(w2, w2t, 1024, 2048,
                                               (long)1024 * 2048, (long)2048 * 1024);

  // 1. ln1 -> xnh (f16)
  k_rmsnorm<<<SDIM, 256, 0, stream>>>(hidden, ln1w, nullptr, xnh);

  // 2. QKV MFMA (fp32 out)
  MArgs a0 = {};
  a0.A = xnh; a0.Bt = qkvt; a0.Kdim = HDIM;
  a0.Cq = Qb; a0.Ck = Kb; a0.Cv = Vb;
  k_mfma<0><<<dim3(48, 16), 256, 0, stream>>>(a0);

  // 3. q/k rmsnorm + rope -> f16; V transpose -> f16 [512][2048]
  k_qknorm_rope<<<SDIM, 256, 0, stream>>>(Qb, qnw, cosb, sinb, NHQ * HD, Qhh);
  k_qknorm_rope<<<SDIM, 256, 0, stream>>>(Kb, knw, cosb, sinb, NKVH * HD, Khh);
  k_convT<<<dim3(8, 32, 1), 256, 0, stream>>>(Vb, Vth, 2048, 512, 0, 0);

  // 4. MFMA flash attention -> AOh (f16)
  k_attn_mfma<<<dim3(SDIM / 64, NHQ), 256, 0, stream>>>(Qhh, Khh, Vth, AOh);

  // 5. wo + residual -> out
  MArgs a1 = {};
  a1.A = AOh; a1.Bt = wot; a1.Kdim = HDIM; a1.C = out; a1.resid = hidden;
  k_mfma<1><<<dim3(32, 16), 256, 0, stream>>>(a1);

  // 6. ln2 -> xn2 (fp32 for gate) + xn2h (f16 for MoE)
  k_rmsnorm<<<SDIM, 256, 0, stream>>>(out, ln2w, xn2, xn2h);

  // 7. routing
  k_gate<<<SDIM, 256, 0, stream>>>(xn2, gatew, logits);
  k_route<<<8, 256, 0, stream>>>(logits, biase, counts, toke, tokrw);
  k_offsets<<<1, 64, 0, stream>>>(counts, aoff);
  k_scatter<<<8, 256, 0, stream>>>(toke, tokrw, aoff, cursor, perm, rwbuf, tokslot);

  // 8. MoE up: G = gather(xn2h) @ [w1|w3]^T (f16 out)
  MArgs a2 = {};
  a2.A = xn2h; a2.Bt = w13t; a2.Kdim = HDIM; a2.Ch = Gbuf;
  a2.perm = perm; a2.aoff = aoff;
  k_mfma<2><<<dim3(32, CAP / 128), 256, 0, stream>>>(a2);

  k_silu<<<CAP, 128, 0, stream>>>(Gbuf, perm, Hbh);

  // 9. MoE down: Yb = (Hb @ w2^T) * rw
  MArgs a3 = {};
  a3.A = Hbh; a3.Bt = w2t; a3.Kdim = IDIM; a3.C = Yb;
  a3.perm = perm; a3.aoff = aoff; a3.rwbuf = rwbuf;
  k_mfma<3><<<dim3(32, CAP / 128), 256, 0, stream>>>(a3);

  // 10. final residual add
  k_fadd<<<SDIM, 256, 0, stream>>>(out, Yb, tokslot);
}